// Round 3
// baseline (270.930 us; speedup 1.0000x reference)
//
#include <hip/hip_runtime.h>
#include <hip/hip_bf16.h>

#define N_NODES 20000
#define N_EDGES 320000
#define DATA_DIM 64
#define H 128

// ---------- tiny precompute: r = relu(b_msg); c = r @ Wu_m; bx = b_emb @ Wu_x ----------
__global__ void k_pre(const float* __restrict__ b_emb,
                      const float* __restrict__ b_msg,
                      const float* __restrict__ W_upd,
                      float* __restrict__ r, float* __restrict__ c,
                      float* __restrict__ bx) {
    int j = threadIdx.x; // 128
    __shared__ float rs[H];
    float rj = fmaxf(b_msg[j], 0.f);
    r[j] = rj;
    rs[j] = rj;
    __syncthreads();
    float cj = 0.f, bxj = 0.f;
    for (int k = 0; k < H; k++) {
        cj  += rs[k] * W_upd[k * H + j];            // Wu_m rows 0..127
        bxj += b_emb[k] * W_upd[(256 + k) * H + j]; // Wu_x rows 256..383
    }
    c[j] = cj;
    bx[j] = bxj;
}

// ---------- Wf = W_emb @ Wu_x  [64,128] ----------
__global__ void k_wf(const float* __restrict__ W_emb,
                     const float* __restrict__ W_upd,
                     float* __restrict__ Wf) {
    int d = blockIdx.x;  // 64 blocks
    int j = threadIdx.x; // 128
    __shared__ float es[H];
    es[j] = W_emb[d * H + j];
    __syncthreads();
    float acc = 0.f;
    for (int k = 0; k < H; k++)
        acc += es[k] * W_upd[(256 + k) * H + j];
    Wf[d * H + j] = acc;
}

// ---------- degree histogram over edge_dst ----------
__global__ void k_deg(const int* __restrict__ dst, int* __restrict__ deg) {
    int e = blockIdx.x * blockDim.x + threadIdx.x;
    if (e < N_EDGES) atomicAdd(&deg[dst[e]], 1);
}

// ---------- exclusive scan -> offs, cursor ----------
__global__ void k_scan(const int* __restrict__ deg, int* __restrict__ offs,
                       int* __restrict__ cursor) {
    __shared__ int buf[1024];
    int t = threadIdx.x;
    const int chunk = (N_NODES + 1023) / 1024; // 20
    int base = t * chunk;
    int s = 0;
    for (int i = 0; i < chunk; i++) {
        int idx = base + i;
        if (idx < N_NODES) s += deg[idx];
    }
    int val = s;
    for (int off = 1; off < 1024; off <<= 1) {
        buf[t] = val;
        __syncthreads();
        if (t >= off) val += buf[t - off];
        __syncthreads();
    }
    int run = val - s;
    for (int i = 0; i < chunk; i++) {
        int idx = base + i;
        if (idx < N_NODES) {
            offs[idx] = run;
            cursor[idx] = run;
            run += deg[idx];
        }
    }
    if (t == 1023) offs[N_NODES] = val;
}

// ---------- bucket-scatter SRC ids by dst ----------
__global__ void k_scatter(const int* __restrict__ dst, const int* __restrict__ src,
                          int* __restrict__ cursor, int* __restrict__ srcp) {
    int e = blockIdx.x * blockDim.x + threadIdx.x;
    if (e < N_EDGES) {
        int p = atomicAdd(&cursor[dst[e]], 1);
        srcp[p] = src[e];
    }
}

// ---------- xu = data @ Wf + bx ; h1 = tanh(deg*c + xu + b_upd) ----------
// 16 nodes/block; thread = (col pair cc,cc+64) x (4 nodes); float4 LDS reads
__global__ void __launch_bounds__(256) k_xu_h1(
        const float* __restrict__ data, const float* __restrict__ Wf,
        const float* __restrict__ bx, const int* __restrict__ deg,
        const float* __restrict__ c, const float* __restrict__ b_upd,
        float* __restrict__ xu, float* __restrict__ h1) {
    __shared__ float ds[16][DATA_DIM]; // 4 KB
    int tid = threadIdx.x;
    int cc = tid & 63, g = tid >> 6;
    int v0 = blockIdx.x * 16;
    for (int idx = tid; idx < 16 * DATA_DIM; idx += 256)
        ds[idx >> 6][idx & 63] = data[v0 * DATA_DIM + idx];
    __syncthreads();
    float a0[4] = {0, 0, 0, 0}, a1[4] = {0, 0, 0, 0};
    for (int k4 = 0; k4 < DATA_DIM; k4 += 4) {
        float4 xv[4];
        #pragma unroll
        for (int i = 0; i < 4; i++)
            xv[i] = *(const float4*)&ds[g * 4 + i][k4];
        #pragma unroll
        for (int q = 0; q < 4; q++) {
            float w0 = Wf[(k4 + q) * H + cc];
            float w1 = Wf[(k4 + q) * H + cc + 64];
            #pragma unroll
            for (int i = 0; i < 4; i++) {
                float x = ((const float*)&xv[i])[q];
                a0[i] += x * w0;
                a1[i] += x * w1;
            }
        }
    }
    float bx0 = bx[cc], bx1 = bx[cc + 64];
    float c0 = c[cc], c1 = c[cc + 64];
    float bu0 = b_upd[cc], bu1 = b_upd[cc + 64];
    #pragma unroll
    for (int i = 0; i < 4; i++) {
        int v = v0 + g * 4 + i;
        float dv = (float)deg[v];
        float x0 = a0[i] + bx0;
        float x1 = a1[i] + bx1;
        xu[v * H + cc] = x0;
        xu[v * H + cc + 64] = x1;
        h1[v * H + cc] = tanhf(dv * c0 + x0 + bu0);
        h1[v * H + cc + 64] = tanhf(dv * c1 + x1 + bu1);
    }
}

// ---------- A = h1 @ Wm_dst (fp32) ; Bb = bf16(h1 @ Wm_src) ----------
__global__ void __launch_bounds__(256) k_ab(
        const float* __restrict__ h1, const float* __restrict__ W_msg,
        float* __restrict__ A, __hip_bfloat16* __restrict__ Bb) {
    __shared__ float hs[16][H]; // 8 KB
    int tid = threadIdx.x;
    int cc = tid & 63, g = tid >> 6;
    int v0 = blockIdx.x * 16;
    for (int idx = tid; idx < 16 * H; idx += 256)
        hs[idx >> 7][idx & 127] = h1[v0 * H + idx];
    __syncthreads();
    float a0[4] = {0, 0, 0, 0}, a1[4] = {0, 0, 0, 0};
    float b0[4] = {0, 0, 0, 0}, b1[4] = {0, 0, 0, 0};
    for (int k4 = 0; k4 < H; k4 += 4) {
        float4 xv[4];
        #pragma unroll
        for (int i = 0; i < 4; i++)
            xv[i] = *(const float4*)&hs[g * 4 + i][k4];
        #pragma unroll
        for (int q = 0; q < 4; q++) {
            float wd0 = W_msg[(k4 + q) * H + cc];
            float wd1 = W_msg[(k4 + q) * H + cc + 64];
            float ws0 = W_msg[(H + k4 + q) * H + cc];
            float ws1 = W_msg[(H + k4 + q) * H + cc + 64];
            #pragma unroll
            for (int i = 0; i < 4; i++) {
                float x = ((const float*)&xv[i])[q];
                a0[i] += x * wd0;
                a1[i] += x * wd1;
                b0[i] += x * ws0;
                b1[i] += x * ws1;
            }
        }
    }
    #pragma unroll
    for (int i = 0; i < 4; i++) {
        int v = v0 + g * 4 + i;
        A[v * H + cc] = a0[i];
        A[v * H + cc + 64] = a1[i];
        Bb[v * H + cc] = __float2bfloat16(b0[i]);
        Bb[v * H + cc + 64] = __float2bfloat16(b1[i]);
    }
}

// ---------- per-node edge reduce: m2 = deg*r + sum_e relu(A[v]+Bb[src]+b_msg) ----------
// m2 aliases A (A[v] read before m2[v] written by the same threads)
__global__ void __launch_bounds__(256) k_edge(
        const int* __restrict__ offs, const int* __restrict__ srcp,
        const float* __restrict__ Afull, const __hip_bfloat16* __restrict__ Bb,
        const float* __restrict__ b_msg, const float* __restrict__ r,
        const int* __restrict__ deg, float* __restrict__ m2) {
    int tid = threadIdx.x;
    int j = tid & 127, g = tid >> 7;
    int v0 = blockIdx.x * 8;
    float bm = b_msg[j], rj = r[j];
    for (int it = 0; it < 4; it++) {
        int v = v0 + it * 2 + g;
        float t = Afull[v * H + j] + bm;
        float acc = (float)deg[v] * rj;
        int e = offs[v], e1 = offs[v + 1];
        for (; e + 4 <= e1; e += 4) {
            int s0 = srcp[e], s1 = srcp[e + 1], s2 = srcp[e + 2], s3 = srcp[e + 3];
            float x0 = __bfloat162float(Bb[s0 * H + j]);
            float x1 = __bfloat162float(Bb[s1 * H + j]);
            float x2 = __bfloat162float(Bb[s2 * H + j]);
            float x3 = __bfloat162float(Bb[s3 * H + j]);
            acc += fmaxf(t + x0, 0.f) + fmaxf(t + x1, 0.f)
                 + fmaxf(t + x2, 0.f) + fmaxf(t + x3, 0.f);
        }
        for (; e < e1; e++) {
            int s = srcp[e];
            acc += fmaxf(t + __bfloat162float(Bb[s * H + j]), 0.f);
        }
        m2[v * H + j] = acc;
    }
}

// ---------- h2 = tanh([m2|h1]@Wu + xu + b_upd); per-block partial column sums ----------
__global__ void __launch_bounds__(256) k_h2sum(
        const float* __restrict__ m2, const float* __restrict__ h1,
        const float* __restrict__ xu, const float* __restrict__ W_upd,
        const float* __restrict__ b_upd, float* __restrict__ partials) {
    __shared__ float xs[16][2 * H]; // 16 KB
    __shared__ float red[4][H];     // 2 KB
    int tid = threadIdx.x;
    int cc = tid & 63, g = tid >> 6;
    int v0 = blockIdx.x * 16;
    for (int idx = tid; idx < 16 * H; idx += 256) {
        xs[idx >> 7][idx & 127] = m2[v0 * H + idx];
        xs[idx >> 7][H + (idx & 127)] = h1[v0 * H + idx];
    }
    __syncthreads();
    float a0[4] = {0, 0, 0, 0}, a1[4] = {0, 0, 0, 0};
    for (int k4 = 0; k4 < 2 * H; k4 += 4) {
        float4 xv[4];
        #pragma unroll
        for (int i = 0; i < 4; i++)
            xv[i] = *(const float4*)&xs[g * 4 + i][k4];
        #pragma unroll
        for (int q = 0; q < 4; q++) {
            float w0 = W_upd[(k4 + q) * H + cc];
            float w1 = W_upd[(k4 + q) * H + cc + 64];
            #pragma unroll
            for (int i = 0; i < 4; i++) {
                float x = ((const float*)&xv[i])[q];
                a0[i] += x * w0;
                a1[i] += x * w1;
            }
        }
    }
    float bu0 = b_upd[cc], bu1 = b_upd[cc + 64];
    float s0 = 0.f, s1 = 0.f;
    #pragma unroll
    for (int i = 0; i < 4; i++) {
        int v = v0 + g * 4 + i;
        s0 += tanhf(a0[i] + xu[v * H + cc] + bu0);
        s1 += tanhf(a1[i] + xu[v * H + cc + 64] + bu1);
    }
    red[g][cc] = s0;
    red[g][cc + 64] = s1;
    __syncthreads();
    if (tid < H)
        partials[blockIdx.x * H + tid] =
            red[0][tid] + red[1][tid] + red[2][tid] + red[3][tid];
}

// ---------- reduce partials; out = relu(ssum @ W_ro + b_ro) ----------
__global__ void __launch_bounds__(1024) k_out(
        const float* __restrict__ partials, int nparts,
        const float* __restrict__ W_ro, const float* __restrict__ b_ro,
        float* __restrict__ out) {
    __shared__ float red[1024];
    __shared__ float ss[H];
    int tid = threadIdx.x;
    int j = tid & 127, g = tid >> 7; // 8 groups
    float s = 0.f;
    for (int b = g; b < nparts; b += 8)
        s += partials[b * H + j];
    red[tid] = s;
    __syncthreads();
    if (tid < H) {
        float tot = 0.f;
        #pragma unroll
        for (int q = 0; q < 8; q++)
            tot += red[q * H + tid];
        ss[tid] = tot;
    }
    __syncthreads();
    if (tid < H) {
        float acc = b_ro[tid];
        for (int k = 0; k < H; k++)
            acc += ss[k] * W_ro[k * H + tid];
        out[tid] = fmaxf(acc, 0.f);
    }
}

extern "C" void kernel_launch(void* const* d_in, const int* in_sizes, int n_in,
                              void* d_out, int out_size, void* d_ws, size_t ws_size,
                              hipStream_t stream) {
    const float* data   = (const float*)d_in[0];
    const int*   esrc   = (const int*)d_in[1];
    const int*   edst   = (const int*)d_in[2];
    const float* W_emb  = (const float*)d_in[3];
    const float* b_emb  = (const float*)d_in[4];
    const float* W_msg  = (const float*)d_in[5];
    const float* b_msg  = (const float*)d_in[6];
    const float* W_upd  = (const float*)d_in[7];
    const float* b_upd  = (const float*)d_in[8];
    const float* W_ro   = (const float*)d_in[9];
    const float* b_ro   = (const float*)d_in[10];
    float* out = (float*)d_out;

    const int NPART = N_NODES / 16; // 1250

    // workspace layout
    float* xu    = (float*)d_ws;            // N*H
    float* h1    = xu + N_NODES * H;        // N*H
    float* A     = h1 + N_NODES * H;        // N*H (becomes m2)
    __hip_bfloat16* Bb = (__hip_bfloat16*)(A + N_NODES * H); // N*H bf16
    float* part  = (float*)(Bb + N_NODES * H); // NPART*H
    float* r     = part + NPART * H;        // H
    float* c     = r + H;                   // H
    float* bx    = c + H;                   // H
    float* Wf    = bx + H;                  // 64*H
    int* degi    = (int*)(Wf + DATA_DIM * H); // N
    int* offs    = degi + N_NODES;          // N+1
    int* cursor  = offs + N_NODES + 1;      // N
    int* srcp    = cursor + N_NODES;        // E

    hipMemsetAsync(degi, 0, N_NODES * sizeof(int), stream);

    k_pre<<<1, H, 0, stream>>>(b_emb, b_msg, W_upd, r, c, bx);
    k_wf<<<DATA_DIM, H, 0, stream>>>(W_emb, W_upd, Wf);
    k_deg<<<(N_EDGES + 255) / 256, 256, 0, stream>>>(edst, degi);
    k_scan<<<1, 1024, 0, stream>>>(degi, offs, cursor);
    k_scatter<<<(N_EDGES + 255) / 256, 256, 0, stream>>>(edst, esrc, cursor, srcp);
    k_xu_h1<<<N_NODES / 16, 256, 0, stream>>>(data, Wf, bx, degi, c, b_upd, xu, h1);
    k_ab<<<N_NODES / 16, 256, 0, stream>>>(h1, W_msg, A, Bb);
    k_edge<<<N_NODES / 8, 256, 0, stream>>>(offs, srcp, A, Bb, b_msg, r, degi, A);
    k_h2sum<<<N_NODES / 16, 256, 0, stream>>>(A, h1, xu, W_upd, b_upd, part);
    k_out<<<1, 1024, 0, stream>>>(part, NPART, W_ro, b_ro, out);
}

// Round 4
// 264.398 us; speedup vs baseline: 1.0247x; 1.0247x over previous
//
#include <hip/hip_runtime.h>
#include <hip/hip_bf16.h>

#define N_NODES 20000
#define N_EDGES 320000
#define DATA_DIM 64
#define H 128

// ---------- tiny precompute: r = relu(b_msg); c = r @ Wu_m; bx = b_emb @ Wu_x ----------
__global__ void k_pre(const float* __restrict__ b_emb,
                      const float* __restrict__ b_msg,
                      const float* __restrict__ W_upd,
                      float* __restrict__ r, float* __restrict__ c,
                      float* __restrict__ bx) {
    int j = threadIdx.x; // 128
    __shared__ float rs[H];
    float rj = fmaxf(b_msg[j], 0.f);
    r[j] = rj;
    rs[j] = rj;
    __syncthreads();
    float cj = 0.f, bxj = 0.f;
    for (int k = 0; k < H; k++) {
        cj  += rs[k] * W_upd[k * H + j];            // Wu_m rows 0..127
        bxj += b_emb[k] * W_upd[(256 + k) * H + j]; // Wu_x rows 256..383
    }
    c[j] = cj;
    bx[j] = bxj;
}

// ---------- Wf = W_emb @ Wu_x  [64,128] ----------
__global__ void k_wf(const float* __restrict__ W_emb,
                     const float* __restrict__ W_upd,
                     float* __restrict__ Wf) {
    int d = blockIdx.x;  // 64 blocks
    int j = threadIdx.x; // 128
    __shared__ float es[H];
    es[j] = W_emb[d * H + j];
    __syncthreads();
    float acc = 0.f;
    for (int k = 0; k < H; k++)
        acc += es[k] * W_upd[(256 + k) * H + j];
    Wf[d * H + j] = acc;
}

// ---------- degree histogram over edge_dst ----------
__global__ void k_deg(const int* __restrict__ dst, int* __restrict__ deg) {
    int e = blockIdx.x * blockDim.x + threadIdx.x;
    if (e < N_EDGES) atomicAdd(&deg[dst[e]], 1);
}

// ---------- exclusive scan -> offs, cursor ----------
__global__ void k_scan(const int* __restrict__ deg, int* __restrict__ offs,
                       int* __restrict__ cursor) {
    __shared__ int buf[1024];
    int t = threadIdx.x;
    const int chunk = (N_NODES + 1023) / 1024; // 20
    int base = t * chunk;
    int s = 0;
    for (int i = 0; i < chunk; i++) {
        int idx = base + i;
        if (idx < N_NODES) s += deg[idx];
    }
    int val = s;
    for (int off = 1; off < 1024; off <<= 1) {
        buf[t] = val;
        __syncthreads();
        if (t >= off) val += buf[t - off];
        __syncthreads();
    }
    int run = val - s;
    for (int i = 0; i < chunk; i++) {
        int idx = base + i;
        if (idx < N_NODES) {
            offs[idx] = run;
            cursor[idx] = run;
            run += deg[idx];
        }
    }
    if (t == 1023) offs[N_NODES] = val;
}

// ---------- bucket-scatter SRC ids by dst ----------
__global__ void k_scatter(const int* __restrict__ dst, const int* __restrict__ src,
                          int* __restrict__ cursor, int* __restrict__ srcp) {
    int e = blockIdx.x * blockDim.x + threadIdx.x;
    if (e < N_EDGES) {
        int p = atomicAdd(&cursor[dst[e]], 1);
        srcp[p] = src[e];
    }
}

// ---------- fused: xu = data@Wf + bx ; h1 = tanh(deg*c + xu + b_upd);
//                   A = h1@Wm_dst (fp32) ; Bb = bf16(h1@Wm_src) ----------
__global__ void __launch_bounds__(256) k_xuh1ab(
        const float* __restrict__ data, const float* __restrict__ Wf,
        const float* __restrict__ bx, const int* __restrict__ deg,
        const float* __restrict__ c, const float* __restrict__ b_upd,
        const float* __restrict__ W_msg,
        float* __restrict__ xu, float* __restrict__ h1,
        float* __restrict__ A, __hip_bfloat16* __restrict__ Bb) {
    __shared__ float ds[16][DATA_DIM]; // 4 KB
    __shared__ float hs[16][H];        // 8 KB
    int tid = threadIdx.x;
    int cc = tid & 63, g = tid >> 6;
    int v0 = blockIdx.x * 16;
    for (int idx = tid; idx < 16 * DATA_DIM; idx += 256)
        ds[idx >> 6][idx & 63] = data[v0 * DATA_DIM + idx];
    __syncthreads();
    float a0[4] = {0, 0, 0, 0}, a1[4] = {0, 0, 0, 0};
    for (int k4 = 0; k4 < DATA_DIM; k4 += 4) {
        float4 xv[4];
        #pragma unroll
        for (int i = 0; i < 4; i++)
            xv[i] = *(const float4*)&ds[g * 4 + i][k4];
        #pragma unroll
        for (int q = 0; q < 4; q++) {
            float w0 = Wf[(k4 + q) * H + cc];
            float w1 = Wf[(k4 + q) * H + cc + 64];
            #pragma unroll
            for (int i = 0; i < 4; i++) {
                float x = ((const float*)&xv[i])[q];
                a0[i] += x * w0;
                a1[i] += x * w1;
            }
        }
    }
    float bx0 = bx[cc], bx1 = bx[cc + 64];
    float c0 = c[cc], c1 = c[cc + 64];
    float bu0 = b_upd[cc], bu1 = b_upd[cc + 64];
    #pragma unroll
    for (int i = 0; i < 4; i++) {
        int v = v0 + g * 4 + i;
        float dv = (float)deg[v];
        float x0 = a0[i] + bx0;
        float x1 = a1[i] + bx1;
        xu[v * H + cc] = x0;
        xu[v * H + cc + 64] = x1;
        float h0 = tanhf(dv * c0 + x0 + bu0);
        float h1v = tanhf(dv * c1 + x1 + bu1);
        h1[v * H + cc] = h0;
        h1[v * H + cc + 64] = h1v;
        hs[g * 4 + i][cc] = h0;
        hs[g * 4 + i][cc + 64] = h1v;
    }
    __syncthreads();
    // ---- A/B part ----
    float p0[4] = {0, 0, 0, 0}, p1[4] = {0, 0, 0, 0};
    float q0[4] = {0, 0, 0, 0}, q1[4] = {0, 0, 0, 0};
    for (int k4 = 0; k4 < H; k4 += 4) {
        float4 xv[4];
        #pragma unroll
        for (int i = 0; i < 4; i++)
            xv[i] = *(const float4*)&hs[g * 4 + i][k4];
        #pragma unroll
        for (int q = 0; q < 4; q++) {
            float wd0 = W_msg[(k4 + q) * H + cc];
            float wd1 = W_msg[(k4 + q) * H + cc + 64];
            float ws0 = W_msg[(H + k4 + q) * H + cc];
            float ws1 = W_msg[(H + k4 + q) * H + cc + 64];
            #pragma unroll
            for (int i = 0; i < 4; i++) {
                float x = ((const float*)&xv[i])[q];
                p0[i] += x * wd0;
                p1[i] += x * wd1;
                q0[i] += x * ws0;
                q1[i] += x * ws1;
            }
        }
    }
    #pragma unroll
    for (int i = 0; i < 4; i++) {
        int v = v0 + g * 4 + i;
        A[v * H + cc] = p0[i];
        A[v * H + cc + 64] = p1[i];
        Bb[v * H + cc] = __float2bfloat16(q0[i]);
        Bb[v * H + cc + 64] = __float2bfloat16(q1[i]);
    }
}

// ---------- per-node edge reduce: m2 = deg*r + sum_e relu(A[v]+Bb[src]+b_msg) ----------
// m2 aliases A (A[v] read before m2[v] written by the same threads)
__global__ void __launch_bounds__(256) k_edge(
        const int* __restrict__ offs, const int* __restrict__ srcp,
        const float* __restrict__ Afull, const __hip_bfloat16* __restrict__ Bb,
        const float* __restrict__ b_msg, const float* __restrict__ r,
        const int* __restrict__ deg, float* __restrict__ m2) {
    int tid = threadIdx.x;
    int j = tid & 127, g = tid >> 7;
    int v0 = blockIdx.x * 8;
    float bm = b_msg[j], rj = r[j];
    for (int it = 0; it < 4; it++) {
        int v = v0 + it * 2 + g;
        float t = Afull[v * H + j] + bm;
        float acc = (float)deg[v] * rj;
        int e = offs[v], e1 = offs[v + 1];
        for (; e + 4 <= e1; e += 4) {
            int s0 = srcp[e], s1 = srcp[e + 1], s2 = srcp[e + 2], s3 = srcp[e + 3];
            float x0 = __bfloat162float(Bb[s0 * H + j]);
            float x1 = __bfloat162float(Bb[s1 * H + j]);
            float x2 = __bfloat162float(Bb[s2 * H + j]);
            float x3 = __bfloat162float(Bb[s3 * H + j]);
            acc += fmaxf(t + x0, 0.f) + fmaxf(t + x1, 0.f)
                 + fmaxf(t + x2, 0.f) + fmaxf(t + x3, 0.f);
        }
        for (; e < e1; e++) {
            int s = srcp[e];
            acc += fmaxf(t + __bfloat162float(Bb[s * H + j]), 0.f);
        }
        m2[v * H + j] = acc;
    }
}

// ---------- h2 = tanh([m2|h1]@Wu + xu + b_upd); atomic column sums into ssum ----------
__global__ void __launch_bounds__(256) k_h2sum(
        const float* __restrict__ m2, const float* __restrict__ h1,
        const float* __restrict__ xu, const float* __restrict__ W_upd,
        const float* __restrict__ b_upd, float* __restrict__ ssum) {
    __shared__ float xs[16][2 * H]; // 16 KB
    __shared__ float red[4][H];     // 2 KB
    int tid = threadIdx.x;
    int cc = tid & 63, g = tid >> 6;
    int v0 = blockIdx.x * 16;
    for (int idx = tid; idx < 16 * H; idx += 256) {
        xs[idx >> 7][idx & 127] = m2[v0 * H + idx];
        xs[idx >> 7][H + (idx & 127)] = h1[v0 * H + idx];
    }
    __syncthreads();
    float a0[4] = {0, 0, 0, 0}, a1[4] = {0, 0, 0, 0};
    for (int k4 = 0; k4 < 2 * H; k4 += 4) {
        float4 xv[4];
        #pragma unroll
        for (int i = 0; i < 4; i++)
            xv[i] = *(const float4*)&xs[g * 4 + i][k4];
        #pragma unroll
        for (int q = 0; q < 4; q++) {
            float w0 = W_upd[(k4 + q) * H + cc];
            float w1 = W_upd[(k4 + q) * H + cc + 64];
            #pragma unroll
            for (int i = 0; i < 4; i++) {
                float x = ((const float*)&xv[i])[q];
                a0[i] += x * w0;
                a1[i] += x * w1;
            }
        }
    }
    float bu0 = b_upd[cc], bu1 = b_upd[cc + 64];
    float s0 = 0.f, s1 = 0.f;
    #pragma unroll
    for (int i = 0; i < 4; i++) {
        int v = v0 + g * 4 + i;
        s0 += tanhf(a0[i] + xu[v * H + cc] + bu0);
        s1 += tanhf(a1[i] + xu[v * H + cc + 64] + bu1);
    }
    red[g][cc] = s0;
    red[g][cc + 64] = s1;
    __syncthreads();
    if (tid < H)
        atomicAdd(&ssum[tid],
                  red[0][tid] + red[1][tid] + red[2][tid] + red[3][tid]);
}

// ---------- out = relu(ssum @ W_ro + b_ro), k-parallel ----------
__global__ void __launch_bounds__(1024) k_out(
        const float* __restrict__ ssum,
        const float* __restrict__ W_ro, const float* __restrict__ b_ro,
        float* __restrict__ out) {
    __shared__ float ss[H];
    __shared__ float red[8][H]; // 4 KB
    int tid = threadIdx.x;
    int j = tid & 127, g = tid >> 7; // 8 k-groups of 16
    if (tid < H) ss[tid] = ssum[tid];
    __syncthreads();
    float s = 0.f;
    #pragma unroll
    for (int q = 0; q < 16; q++) {
        int k = g * 16 + q;
        s += ss[k] * W_ro[k * H + j];
    }
    red[g][j] = s;
    __syncthreads();
    if (tid < H) {
        float acc = b_ro[tid];
        #pragma unroll
        for (int q = 0; q < 8; q++)
            acc += red[q][tid];
        out[tid] = fmaxf(acc, 0.f);
    }
}

extern "C" void kernel_launch(void* const* d_in, const int* in_sizes, int n_in,
                              void* d_out, int out_size, void* d_ws, size_t ws_size,
                              hipStream_t stream) {
    const float* data   = (const float*)d_in[0];
    const int*   esrc   = (const int*)d_in[1];
    const int*   edst   = (const int*)d_in[2];
    const float* W_emb  = (const float*)d_in[3];
    const float* b_emb  = (const float*)d_in[4];
    const float* W_msg  = (const float*)d_in[5];
    const float* b_msg  = (const float*)d_in[6];
    const float* W_upd  = (const float*)d_in[7];
    const float* b_upd  = (const float*)d_in[8];
    const float* W_ro   = (const float*)d_in[9];
    const float* b_ro   = (const float*)d_in[10];
    float* out = (float*)d_out;

    // workspace layout
    float* xu    = (float*)d_ws;            // N*H
    float* h1    = xu + N_NODES * H;        // N*H
    float* A     = h1 + N_NODES * H;        // N*H (becomes m2)
    __hip_bfloat16* Bb = (__hip_bfloat16*)(A + N_NODES * H); // N*H bf16
    float* ssum  = (float*)(Bb + N_NODES * H); // H
    float* r     = ssum + H;                // H
    float* c     = r + H;                   // H
    float* bx    = c + H;                   // H
    float* Wf    = bx + H;                  // 64*H
    int* degi    = (int*)(Wf + DATA_DIM * H); // N
    int* offs    = degi + N_NODES;          // N+1
    int* cursor  = offs + N_NODES + 1;      // N
    int* srcp    = cursor + N_NODES;        // E

    hipMemsetAsync(degi, 0, N_NODES * sizeof(int), stream);
    hipMemsetAsync(ssum, 0, H * sizeof(float), stream);

    k_pre<<<1, H, 0, stream>>>(b_emb, b_msg, W_upd, r, c, bx);
    k_wf<<<DATA_DIM, H, 0, stream>>>(W_emb, W_upd, Wf);
    k_deg<<<(N_EDGES + 255) / 256, 256, 0, stream>>>(edst, degi);
    k_scan<<<1, 1024, 0, stream>>>(degi, offs, cursor);
    k_scatter<<<(N_EDGES + 255) / 256, 256, 0, stream>>>(edst, esrc, cursor, srcp);
    k_xuh1ab<<<N_NODES / 16, 256, 0, stream>>>(data, Wf, bx, degi, c, b_upd,
                                               W_msg, xu, h1, A, Bb);
    k_edge<<<N_NODES / 8, 256, 0, stream>>>(offs, srcp, A, Bb, b_msg, r, degi, A);
    k_h2sum<<<N_NODES / 16, 256, 0, stream>>>(A, h1, xu, W_upd, b_upd, ssum);
    k_out<<<1, 1024, 0, stream>>>(ssum, W_ro, b_ro, out);
}

// Round 5
// 231.529 us; speedup vs baseline: 1.1702x; 1.1420x over previous
//
#include <hip/hip_runtime.h>
#include <hip/hip_bf16.h>

#define N_NODES 20000
#define N_EDGES 320000
#define DATA_DIM 64
#define H 128

// ---------- fused tiny precompute ----------
// blocks 0..63: Wf[d] = W_emb[d] @ Wu_x ; block 64: r, c, bx
__global__ void k_prewf(const float* __restrict__ W_emb,
                        const float* __restrict__ W_upd,
                        const float* __restrict__ b_emb,
                        const float* __restrict__ b_msg,
                        float* __restrict__ Wf, float* __restrict__ r,
                        float* __restrict__ c, float* __restrict__ bx) {
    int d = blockIdx.x;
    int j = threadIdx.x; // 128
    __shared__ float sh[H];
    if (d < DATA_DIM) {
        sh[j] = W_emb[d * H + j];
        __syncthreads();
        float acc = 0.f;
        for (int k = 0; k < H; k++)
            acc += sh[k] * W_upd[(256 + k) * H + j];
        Wf[d * H + j] = acc;
    } else {
        float rj = fmaxf(b_msg[j], 0.f);
        r[j] = rj;
        sh[j] = rj;
        __syncthreads();
        float cj = 0.f, bxj = 0.f;
        for (int k = 0; k < H; k++) {
            cj  += sh[k] * W_upd[k * H + j];            // Wu_m rows 0..127
            bxj += b_emb[k] * W_upd[(256 + k) * H + j]; // Wu_x rows 256..383
        }
        c[j] = cj;
        bx[j] = bxj;
    }
}

// ---------- degree histogram over edge_dst ----------
__global__ void k_deg(const int* __restrict__ dst, int* __restrict__ deg) {
    int e = blockIdx.x * blockDim.x + threadIdx.x;
    if (e < N_EDGES) atomicAdd(&deg[dst[e]], 1);
}

// ---------- exclusive scan -> offs, cursor ----------
__global__ void k_scan(const int* __restrict__ deg, int* __restrict__ offs,
                       int* __restrict__ cursor) {
    __shared__ int buf[1024];
    int t = threadIdx.x;
    const int chunk = (N_NODES + 1023) / 1024; // 20
    int base = t * chunk;
    int s = 0;
    for (int i = 0; i < chunk; i++) {
        int idx = base + i;
        if (idx < N_NODES) s += deg[idx];
    }
    int val = s;
    for (int off = 1; off < 1024; off <<= 1) {
        buf[t] = val;
        __syncthreads();
        if (t >= off) val += buf[t - off];
        __syncthreads();
    }
    int run = val - s;
    for (int i = 0; i < chunk; i++) {
        int idx = base + i;
        if (idx < N_NODES) {
            offs[idx] = run;
            cursor[idx] = run;
            run += deg[idx];
        }
    }
    if (t == 1023) offs[N_NODES] = val;
}

// ---------- bucket-scatter SRC ids by dst ----------
__global__ void k_scatter(const int* __restrict__ dst, const int* __restrict__ src,
                          int* __restrict__ cursor, int* __restrict__ srcp) {
    int e = blockIdx.x * blockDim.x + threadIdx.x;
    if (e < N_EDGES) {
        int p = atomicAdd(&cursor[dst[e]], 1);
        srcp[p] = src[e];
    }
}

// ---------- xu = data @ Wf + bx ; h1 = tanh(deg*c + xu + b_upd) ----------
__global__ void __launch_bounds__(256) k_xu_h1(
        const float* __restrict__ data, const float* __restrict__ Wf,
        const float* __restrict__ bx, const int* __restrict__ deg,
        const float* __restrict__ c, const float* __restrict__ b_upd,
        float* __restrict__ xu, float* __restrict__ h1) {
    __shared__ float ds[16][DATA_DIM]; // 4 KB
    int tid = threadIdx.x;
    int cc = tid & 63, g = tid >> 6;
    int v0 = blockIdx.x * 16;
    for (int idx = tid; idx < 16 * DATA_DIM; idx += 256)
        ds[idx >> 6][idx & 63] = data[v0 * DATA_DIM + idx];
    __syncthreads();
    float a0[4] = {0, 0, 0, 0}, a1[4] = {0, 0, 0, 0};
    for (int k4 = 0; k4 < DATA_DIM; k4 += 4) {
        float4 xv[4];
        #pragma unroll
        for (int i = 0; i < 4; i++)
            xv[i] = *(const float4*)&ds[g * 4 + i][k4];
        #pragma unroll
        for (int q = 0; q < 4; q++) {
            float w0 = Wf[(k4 + q) * H + cc];
            float w1 = Wf[(k4 + q) * H + cc + 64];
            #pragma unroll
            for (int i = 0; i < 4; i++) {
                float x = ((const float*)&xv[i])[q];
                a0[i] += x * w0;
                a1[i] += x * w1;
            }
        }
    }
    float bx0 = bx[cc], bx1 = bx[cc + 64];
    float c0 = c[cc], c1 = c[cc + 64];
    float bu0 = b_upd[cc], bu1 = b_upd[cc + 64];
    #pragma unroll
    for (int i = 0; i < 4; i++) {
        int v = v0 + g * 4 + i;
        float dv = (float)deg[v];
        float x0 = a0[i] + bx0;
        float x1 = a1[i] + bx1;
        xu[v * H + cc] = x0;
        xu[v * H + cc + 64] = x1;
        h1[v * H + cc] = tanhf(dv * c0 + x0 + bu0);
        h1[v * H + cc + 64] = tanhf(dv * c1 + x1 + bu1);
    }
}

// ---------- A = h1 @ Wm_dst (fp32) ; Bb = bf16(h1 @ Wm_src) ----------
__global__ void __launch_bounds__(256) k_ab(
        const float* __restrict__ h1, const float* __restrict__ W_msg,
        float* __restrict__ A, __hip_bfloat16* __restrict__ Bb) {
    __shared__ float hs[16][H]; // 8 KB
    int tid = threadIdx.x;
    int cc = tid & 63, g = tid >> 6;
    int v0 = blockIdx.x * 16;
    for (int idx = tid; idx < 16 * H; idx += 256)
        hs[idx >> 7][idx & 127] = h1[v0 * H + idx];
    __syncthreads();
    float a0[4] = {0, 0, 0, 0}, a1[4] = {0, 0, 0, 0};
    float b0[4] = {0, 0, 0, 0}, b1[4] = {0, 0, 0, 0};
    for (int k4 = 0; k4 < H; k4 += 4) {
        float4 xv[4];
        #pragma unroll
        for (int i = 0; i < 4; i++)
            xv[i] = *(const float4*)&hs[g * 4 + i][k4];
        #pragma unroll
        for (int q = 0; q < 4; q++) {
            float wd0 = W_msg[(k4 + q) * H + cc];
            float wd1 = W_msg[(k4 + q) * H + cc + 64];
            float ws0 = W_msg[(H + k4 + q) * H + cc];
            float ws1 = W_msg[(H + k4 + q) * H + cc + 64];
            #pragma unroll
            for (int i = 0; i < 4; i++) {
                float x = ((const float*)&xv[i])[q];
                a0[i] += x * wd0;
                a1[i] += x * wd1;
                b0[i] += x * ws0;
                b1[i] += x * ws1;
            }
        }
    }
    #pragma unroll
    for (int i = 0; i < 4; i++) {
        int v = v0 + g * 4 + i;
        A[v * H + cc] = a0[i];
        A[v * H + cc + 64] = a1[i];
        Bb[v * H + cc] = __float2bfloat16(b0[i]);
        Bb[v * H + cc + 64] = __float2bfloat16(b1[i]);
    }
}

// ---------- fused: m2 (in LDS) = deg*r + sum_e relu(A[v]+Bb[src]+b_msg);
//            h2 = tanh([m2|h1]@Wu + xu + b_upd); atomic col-sums into ssum ----------
__global__ void __launch_bounds__(256) k_edge_h2(
        const int* __restrict__ offs, const int* __restrict__ srcp,
        const float* __restrict__ A, const __hip_bfloat16* __restrict__ Bb,
        const float* __restrict__ b_msg, const float* __restrict__ r,
        const int* __restrict__ deg, const float* __restrict__ h1,
        const float* __restrict__ xu, const float* __restrict__ W_upd,
        const float* __restrict__ b_upd, float* __restrict__ ssum) {
    __shared__ float xs[16][2 * H]; // 16 KB : [m2 | h1]
    __shared__ float red[4][H];     // 2 KB
    int tid = threadIdx.x;
    int v0 = blockIdx.x * 16;
    // ---- edge phase: 2 nodes in flight (g=tid>>7), 8 iterations ----
    {
        int j = tid & 127, g = tid >> 7;
        float bm = b_msg[j], rj = r[j];
        for (int it = 0; it < 8; it++) {
            int n = it * 2 + g;
            int v = v0 + n;
            float t = A[v * H + j] + bm;
            float acc = (float)deg[v] * rj;
            int e = offs[v], e1 = offs[v + 1];
            for (; e + 4 <= e1; e += 4) {
                int s0 = srcp[e], s1 = srcp[e + 1], s2 = srcp[e + 2], s3 = srcp[e + 3];
                float x0 = __bfloat162float(Bb[s0 * H + j]);
                float x1 = __bfloat162float(Bb[s1 * H + j]);
                float x2 = __bfloat162float(Bb[s2 * H + j]);
                float x3 = __bfloat162float(Bb[s3 * H + j]);
                acc += fmaxf(t + x0, 0.f) + fmaxf(t + x1, 0.f)
                     + fmaxf(t + x2, 0.f) + fmaxf(t + x3, 0.f);
            }
            for (; e < e1; e++) {
                int s = srcp[e];
                acc += fmaxf(t + __bfloat162float(Bb[s * H + j]), 0.f);
            }
            xs[n][j] = acc; // m2 stays in LDS
        }
        // stage h1 alongside
        for (int idx = tid; idx < 16 * H; idx += 256)
            xs[idx >> 7][H + (idx & 127)] = h1[v0 * H + idx];
    }
    __syncthreads();
    // ---- matmul phase: thread = (col pair) x (4 nodes) ----
    int cc = tid & 63, g = tid >> 6;
    float a0[4] = {0, 0, 0, 0}, a1[4] = {0, 0, 0, 0};
    for (int k4 = 0; k4 < 2 * H; k4 += 4) {
        float4 xv[4];
        #pragma unroll
        for (int i = 0; i < 4; i++)
            xv[i] = *(const float4*)&xs[g * 4 + i][k4];
        #pragma unroll
        for (int q = 0; q < 4; q++) {
            float w0 = W_upd[(k4 + q) * H + cc];
            float w1 = W_upd[(k4 + q) * H + cc + 64];
            #pragma unroll
            for (int i = 0; i < 4; i++) {
                float x = ((const float*)&xv[i])[q];
                a0[i] += x * w0;
                a1[i] += x * w1;
            }
        }
    }
    float bu0 = b_upd[cc], bu1 = b_upd[cc + 64];
    float s0 = 0.f, s1 = 0.f;
    #pragma unroll
    for (int i = 0; i < 4; i++) {
        int v = v0 + g * 4 + i;
        s0 += tanhf(a0[i] + xu[v * H + cc] + bu0);
        s1 += tanhf(a1[i] + xu[v * H + cc + 64] + bu1);
    }
    red[g][cc] = s0;
    red[g][cc + 64] = s1;
    __syncthreads();
    if (tid < H)
        atomicAdd(&ssum[tid],
                  red[0][tid] + red[1][tid] + red[2][tid] + red[3][tid]);
}

// ---------- out = relu(ssum @ W_ro + b_ro), k-parallel ----------
__global__ void __launch_bounds__(1024) k_out(
        const float* __restrict__ ssum,
        const float* __restrict__ W_ro, const float* __restrict__ b_ro,
        float* __restrict__ out) {
    __shared__ float ss[H];
    __shared__ float red[8][H]; // 4 KB
    int tid = threadIdx.x;
    int j = tid & 127, g = tid >> 7; // 8 k-groups of 16
    if (tid < H) ss[tid] = ssum[tid];
    __syncthreads();
    float s = 0.f;
    #pragma unroll
    for (int q = 0; q < 16; q++) {
        int k = g * 16 + q;
        s += ss[k] * W_ro[k * H + j];
    }
    red[g][j] = s;
    __syncthreads();
    if (tid < H) {
        float acc = b_ro[tid];
        #pragma unroll
        for (int q = 0; q < 8; q++)
            acc += red[q][tid];
        out[tid] = fmaxf(acc, 0.f);
    }
}

extern "C" void kernel_launch(void* const* d_in, const int* in_sizes, int n_in,
                              void* d_out, int out_size, void* d_ws, size_t ws_size,
                              hipStream_t stream) {
    const float* data   = (const float*)d_in[0];
    const int*   esrc   = (const int*)d_in[1];
    const int*   edst   = (const int*)d_in[2];
    const float* W_emb  = (const float*)d_in[3];
    const float* b_emb  = (const float*)d_in[4];
    const float* W_msg  = (const float*)d_in[5];
    const float* b_msg  = (const float*)d_in[6];
    const float* W_upd  = (const float*)d_in[7];
    const float* b_upd  = (const float*)d_in[8];
    const float* W_ro   = (const float*)d_in[9];
    const float* b_ro   = (const float*)d_in[10];
    float* out = (float*)d_out;

    // workspace layout
    float* xu    = (float*)d_ws;            // N*H
    float* h1    = xu + N_NODES * H;        // N*H
    float* A     = h1 + N_NODES * H;        // N*H
    __hip_bfloat16* Bb = (__hip_bfloat16*)(A + N_NODES * H); // N*H bf16
    float* ssum  = (float*)(Bb + N_NODES * H); // H
    float* r     = ssum + H;                // H
    float* c     = r + H;                   // H
    float* bx    = c + H;                   // H
    float* Wf    = bx + H;                  // 64*H
    int* degi    = (int*)(Wf + DATA_DIM * H); // N
    int* offs    = degi + N_NODES;          // N+1
    int* cursor  = offs + N_NODES + 1;      // N
    int* srcp    = cursor + N_NODES;        // E

    hipMemsetAsync(degi, 0, N_NODES * sizeof(int), stream);
    hipMemsetAsync(ssum, 0, H * sizeof(float), stream);

    k_prewf<<<DATA_DIM + 1, H, 0, stream>>>(W_emb, W_upd, b_emb, b_msg, Wf, r, c, bx);
    k_deg<<<(N_EDGES + 255) / 256, 256, 0, stream>>>(edst, degi);
    k_scan<<<1, 1024, 0, stream>>>(degi, offs, cursor);
    k_scatter<<<(N_EDGES + 255) / 256, 256, 0, stream>>>(edst, esrc, cursor, srcp);
    k_xu_h1<<<N_NODES / 16, 256, 0, stream>>>(data, Wf, bx, degi, c, b_upd, xu, h1);
    k_ab<<<N_NODES / 16, 256, 0, stream>>>(h1, W_msg, A, Bb);
    k_edge_h2<<<N_NODES / 16, 256, 0, stream>>>(offs, srcp, A, Bb, b_msg, r, degi,
                                                h1, xu, W_upd, b_upd, ssum);
    k_out<<<1, 1024, 0, stream>>>(ssum, W_ro, b_ro, out);
}

// Round 6
// 222.623 us; speedup vs baseline: 1.2170x; 1.0400x over previous
//
#include <hip/hip_runtime.h>
#include <hip/hip_bf16.h>

#define N_NODES 20000
#define N_EDGES 320000
#define DATA_DIM 64
#define H 128

// ---------- fused tiny precompute ----------
// blocks 0..63: Wf[d] = W_emb[d] @ Wu_x ; block 64: r, c, bx
__global__ void k_prewf(const float* __restrict__ W_emb,
                        const float* __restrict__ W_upd,
                        const float* __restrict__ b_emb,
                        const float* __restrict__ b_msg,
                        float* __restrict__ Wf, float* __restrict__ r,
                        float* __restrict__ c, float* __restrict__ bx) {
    int d = blockIdx.x;
    int j = threadIdx.x; // 128
    __shared__ float sh[H];
    if (d < DATA_DIM) {
        sh[j] = W_emb[d * H + j];
        __syncthreads();
        float acc = 0.f;
        for (int k = 0; k < H; k++)
            acc += sh[k] * W_upd[(256 + k) * H + j];
        Wf[d * H + j] = acc;
    } else {
        float rj = fmaxf(b_msg[j], 0.f);
        r[j] = rj;
        sh[j] = rj;
        __syncthreads();
        float cj = 0.f, bxj = 0.f;
        for (int k = 0; k < H; k++) {
            cj  += sh[k] * W_upd[k * H + j];            // Wu_m rows 0..127
            bxj += b_emb[k] * W_upd[(256 + k) * H + j]; // Wu_x rows 256..383
        }
        c[j] = cj;
        bx[j] = bxj;
    }
}

// ---------- degree histogram over edge_dst ----------
__global__ void k_deg(const int* __restrict__ dst, int* __restrict__ deg) {
    int e = blockIdx.x * blockDim.x + threadIdx.x;
    if (e < N_EDGES) atomicAdd(&deg[dst[e]], 1);
}

// ---------- exclusive scan -> offs, cursor ----------
__global__ void k_scan(const int* __restrict__ deg, int* __restrict__ offs,
                       int* __restrict__ cursor) {
    __shared__ int buf[1024];
    int t = threadIdx.x;
    const int chunk = (N_NODES + 1023) / 1024; // 20
    int base = t * chunk;
    int s = 0;
    for (int i = 0; i < chunk; i++) {
        int idx = base + i;
        if (idx < N_NODES) s += deg[idx];
    }
    int val = s;
    for (int off = 1; off < 1024; off <<= 1) {
        buf[t] = val;
        __syncthreads();
        if (t >= off) val += buf[t - off];
        __syncthreads();
    }
    int run = val - s;
    for (int i = 0; i < chunk; i++) {
        int idx = base + i;
        if (idx < N_NODES) {
            offs[idx] = run;
            cursor[idx] = run;
            run += deg[idx];
        }
    }
    if (t == 1023) offs[N_NODES] = val;
}

// ---------- bucket-scatter SRC ids by dst ----------
__global__ void k_scatter(const int* __restrict__ dst, const int* __restrict__ src,
                          int* __restrict__ cursor, int* __restrict__ srcp) {
    int e = blockIdx.x * blockDim.x + threadIdx.x;
    if (e < N_EDGES) {
        int p = atomicAdd(&cursor[dst[e]], 1);
        srcp[p] = src[e];
    }
}

// ---------- xu = data @ Wf + bx ; h1 = tanh(deg*c + xu + b_upd) ----------
__global__ void __launch_bounds__(256) k_xu_h1(
        const float* __restrict__ data, const float* __restrict__ Wf,
        const float* __restrict__ bx, const int* __restrict__ deg,
        const float* __restrict__ c, const float* __restrict__ b_upd,
        float* __restrict__ xu, float* __restrict__ h1) {
    __shared__ float ds[16][DATA_DIM]; // 4 KB
    int tid = threadIdx.x;
    int cc = tid & 63, g = tid >> 6;
    int v0 = blockIdx.x * 16;
    for (int idx = tid; idx < 16 * DATA_DIM; idx += 256)
        ds[idx >> 6][idx & 63] = data[v0 * DATA_DIM + idx];
    __syncthreads();
    float a0[4] = {0, 0, 0, 0}, a1[4] = {0, 0, 0, 0};
    for (int k4 = 0; k4 < DATA_DIM; k4 += 4) {
        float4 xv[4];
        #pragma unroll
        for (int i = 0; i < 4; i++)
            xv[i] = *(const float4*)&ds[g * 4 + i][k4];
        #pragma unroll
        for (int q = 0; q < 4; q++) {
            float w0 = Wf[(k4 + q) * H + cc];
            float w1 = Wf[(k4 + q) * H + cc + 64];
            #pragma unroll
            for (int i = 0; i < 4; i++) {
                float x = ((const float*)&xv[i])[q];
                a0[i] += x * w0;
                a1[i] += x * w1;
            }
        }
    }
    float bx0 = bx[cc], bx1 = bx[cc + 64];
    float c0 = c[cc], c1 = c[cc + 64];
    float bu0 = b_upd[cc], bu1 = b_upd[cc + 64];
    #pragma unroll
    for (int i = 0; i < 4; i++) {
        int v = v0 + g * 4 + i;
        float dv = (float)deg[v];
        float x0 = a0[i] + bx0;
        float x1 = a1[i] + bx1;
        xu[v * H + cc] = x0;
        xu[v * H + cc + 64] = x1;
        h1[v * H + cc] = tanhf(dv * c0 + x0 + bu0);
        h1[v * H + cc + 64] = tanhf(dv * c1 + x1 + bu1);
    }
}

// ---------- A = h1 @ Wm_dst + b_msg (fp32) ; Bb = bf16(h1 @ Wm_src) ----------
__global__ void __launch_bounds__(256) k_ab(
        const float* __restrict__ h1, const float* __restrict__ W_msg,
        const float* __restrict__ b_msg,
        float* __restrict__ A, __hip_bfloat16* __restrict__ Bb) {
    __shared__ float hs[16][H]; // 8 KB
    int tid = threadIdx.x;
    int cc = tid & 63, g = tid >> 6;
    int v0 = blockIdx.x * 16;
    for (int idx = tid; idx < 16 * H; idx += 256)
        hs[idx >> 7][idx & 127] = h1[v0 * H + idx];
    __syncthreads();
    float a0[4] = {0, 0, 0, 0}, a1[4] = {0, 0, 0, 0};
    float b0[4] = {0, 0, 0, 0}, b1[4] = {0, 0, 0, 0};
    for (int k4 = 0; k4 < H; k4 += 4) {
        float4 xv[4];
        #pragma unroll
        for (int i = 0; i < 4; i++)
            xv[i] = *(const float4*)&hs[g * 4 + i][k4];
        #pragma unroll
        for (int q = 0; q < 4; q++) {
            float wd0 = W_msg[(k4 + q) * H + cc];
            float wd1 = W_msg[(k4 + q) * H + cc + 64];
            float ws0 = W_msg[(H + k4 + q) * H + cc];
            float ws1 = W_msg[(H + k4 + q) * H + cc + 64];
            #pragma unroll
            for (int i = 0; i < 4; i++) {
                float x = ((const float*)&xv[i])[q];
                a0[i] += x * wd0;
                a1[i] += x * wd1;
                b0[i] += x * ws0;
                b1[i] += x * ws1;
            }
        }
    }
    float bm0 = b_msg[cc], bm1 = b_msg[cc + 64];
    #pragma unroll
    for (int i = 0; i < 4; i++) {
        int v = v0 + g * 4 + i;
        A[v * H + cc] = a0[i] + bm0;
        A[v * H + cc + 64] = a1[i] + bm1;
        Bb[v * H + cc] = __float2bfloat16(b0[i]);
        Bb[v * H + cc + 64] = __float2bfloat16(b1[i]);
    }
}

// ---------- fused: m2 (in LDS) = deg*r + sum_e relu(A'[v]+Bb[src]);
//            h2 = tanh([m2|h1]@Wu + xu + b_upd); atomic col-sums into ssum ----------
// Edge phase: wave = 1 node, lane covers cols (2l, 2l+1); src id made wave-uniform
// via readlane so the gather is SGPR-base + lane*4 (one 256B row per edge).
__global__ void __launch_bounds__(256) k_edge_h2(
        const int* __restrict__ offs, const int* __restrict__ srcp,
        const float* __restrict__ A, const unsigned short* __restrict__ Bb,
        const float* __restrict__ r, const float* __restrict__ h1,
        const float* __restrict__ xu, const float* __restrict__ W_upd,
        const float* __restrict__ b_upd, float* __restrict__ ssum) {
    __shared__ float xs[16][2 * H]; // 16 KB : [m2 | h1]
    __shared__ float red[4][H];     // 2 KB
    int tid = threadIdx.x;
    int lane = tid & 63, w = tid >> 6;
    int v0 = blockIdx.x * 16;
    // ---- edge phase: each wave owns 4 nodes ----
    {
        const float2* r2 = (const float2*)r;
        float2 rr = r2[lane];
        for (int it = 0; it < 4; it++) {
            int n = w * 4 + it;
            int v = v0 + n;
            const float2* A2 = (const float2*)(A + v * H);
            float2 av = A2[lane];
            float t0 = av.x, t1 = av.y;
            int e0 = offs[v], e1 = offs[v + 1];
            float dv = (float)(e1 - e0);
            float acc0 = dv * rr.x, acc1 = dv * rr.y;
            while (e0 < e1) {
                int cnt = e1 - e0;
                if (cnt > 64) cnt = 64;
                int sv = (lane < cnt) ? srcp[e0 + lane] : 0;
                int i = 0;
                for (; i + 4 <= cnt; i += 4) {
                    int s0 = __builtin_amdgcn_readlane(sv, i);
                    int s1 = __builtin_amdgcn_readlane(sv, i + 1);
                    int s2 = __builtin_amdgcn_readlane(sv, i + 2);
                    int s3 = __builtin_amdgcn_readlane(sv, i + 3);
                    unsigned u0 = *(const unsigned*)(Bb + (size_t)s0 * H + 2 * lane);
                    unsigned u1 = *(const unsigned*)(Bb + (size_t)s1 * H + 2 * lane);
                    unsigned u2 = *(const unsigned*)(Bb + (size_t)s2 * H + 2 * lane);
                    unsigned u3 = *(const unsigned*)(Bb + (size_t)s3 * H + 2 * lane);
                    acc0 += fmaxf(t0 + __uint_as_float(u0 << 16), 0.f);
                    acc1 += fmaxf(t1 + __uint_as_float(u0 & 0xffff0000u), 0.f);
                    acc0 += fmaxf(t0 + __uint_as_float(u1 << 16), 0.f);
                    acc1 += fmaxf(t1 + __uint_as_float(u1 & 0xffff0000u), 0.f);
                    acc0 += fmaxf(t0 + __uint_as_float(u2 << 16), 0.f);
                    acc1 += fmaxf(t1 + __uint_as_float(u2 & 0xffff0000u), 0.f);
                    acc0 += fmaxf(t0 + __uint_as_float(u3 << 16), 0.f);
                    acc1 += fmaxf(t1 + __uint_as_float(u3 & 0xffff0000u), 0.f);
                }
                for (; i < cnt; i++) {
                    int s = __builtin_amdgcn_readlane(sv, i);
                    unsigned u = *(const unsigned*)(Bb + (size_t)s * H + 2 * lane);
                    acc0 += fmaxf(t0 + __uint_as_float(u << 16), 0.f);
                    acc1 += fmaxf(t1 + __uint_as_float(u & 0xffff0000u), 0.f);
                }
                e0 += cnt;
            }
            *(float2*)&xs[n][2 * lane] = make_float2(acc0, acc1);
        }
        // stage h1 alongside
        for (int idx = tid; idx < 16 * H; idx += 256)
            xs[idx >> 7][H + (idx & 127)] = h1[v0 * H + idx];
    }
    __syncthreads();
    // ---- matmul phase: thread = (col pair) x (4 nodes) ----
    int cc = tid & 63, g = tid >> 6;
    float a0[4] = {0, 0, 0, 0}, a1[4] = {0, 0, 0, 0};
    for (int k4 = 0; k4 < 2 * H; k4 += 4) {
        float4 xv[4];
        #pragma unroll
        for (int i = 0; i < 4; i++)
            xv[i] = *(const float4*)&xs[g * 4 + i][k4];
        #pragma unroll
        for (int q = 0; q < 4; q++) {
            float w0 = W_upd[(k4 + q) * H + cc];
            float w1 = W_upd[(k4 + q) * H + cc + 64];
            #pragma unroll
            for (int i = 0; i < 4; i++) {
                float x = ((const float*)&xv[i])[q];
                a0[i] += x * w0;
                a1[i] += x * w1;
            }
        }
    }
    float bu0 = b_upd[cc], bu1 = b_upd[cc + 64];
    float s0 = 0.f, s1 = 0.f;
    #pragma unroll
    for (int i = 0; i < 4; i++) {
        int v = v0 + g * 4 + i;
        s0 += tanhf(a0[i] + xu[v * H + cc] + bu0);
        s1 += tanhf(a1[i] + xu[v * H + cc + 64] + bu1);
    }
    red[g][cc] = s0;
    red[g][cc + 64] = s1;
    __syncthreads();
    if (tid < H)
        atomicAdd(&ssum[tid],
                  red[0][tid] + red[1][tid] + red[2][tid] + red[3][tid]);
}

// ---------- out = relu(ssum @ W_ro + b_ro), k-parallel ----------
__global__ void __launch_bounds__(1024) k_out(
        const float* __restrict__ ssum,
        const float* __restrict__ W_ro, const float* __restrict__ b_ro,
        float* __restrict__ out) {
    __shared__ float ss[H];
    __shared__ float red[8][H]; // 4 KB
    int tid = threadIdx.x;
    int j = tid & 127, g = tid >> 7; // 8 k-groups of 16
    if (tid < H) ss[tid] = ssum[tid];
    __syncthreads();
    float s = 0.f;
    #pragma unroll
    for (int q = 0; q < 16; q++) {
        int k = g * 16 + q;
        s += ss[k] * W_ro[k * H + j];
    }
    red[g][j] = s;
    __syncthreads();
    if (tid < H) {
        float acc = b_ro[tid];
        #pragma unroll
        for (int q = 0; q < 8; q++)
            acc += red[q][tid];
        out[tid] = fmaxf(acc, 0.f);
    }
}

extern "C" void kernel_launch(void* const* d_in, const int* in_sizes, int n_in,
                              void* d_out, int out_size, void* d_ws, size_t ws_size,
                              hipStream_t stream) {
    const float* data   = (const float*)d_in[0];
    const int*   esrc   = (const int*)d_in[1];
    const int*   edst   = (const int*)d_in[2];
    const float* W_emb  = (const float*)d_in[3];
    const float* b_emb  = (const float*)d_in[4];
    const float* W_msg  = (const float*)d_in[5];
    const float* b_msg  = (const float*)d_in[6];
    const float* W_upd  = (const float*)d_in[7];
    const float* b_upd  = (const float*)d_in[8];
    const float* W_ro   = (const float*)d_in[9];
    const float* b_ro   = (const float*)d_in[10];
    float* out = (float*)d_out;

    // workspace layout
    float* xu    = (float*)d_ws;            // N*H
    float* h1    = xu + N_NODES * H;        // N*H
    float* A     = h1 + N_NODES * H;        // N*H
    __hip_bfloat16* Bb = (__hip_bfloat16*)(A + N_NODES * H); // N*H bf16
    float* ssum  = (float*)(Bb + N_NODES * H); // H
    float* r     = ssum + H;                // H
    float* c     = r + H;                   // H
    float* bx    = c + H;                   // H
    float* Wf    = bx + H;                  // 64*H
    int* degi    = (int*)(Wf + DATA_DIM * H); // N
    int* offs    = degi + N_NODES;          // N+1
    int* cursor  = offs + N_NODES + 1;      // N
    int* srcp    = cursor + N_NODES;        // E

    hipMemsetAsync(degi, 0, N_NODES * sizeof(int), stream);
    hipMemsetAsync(ssum, 0, H * sizeof(float), stream);

    k_prewf<<<DATA_DIM + 1, H, 0, stream>>>(W_emb, W_upd, b_emb, b_msg, Wf, r, c, bx);
    k_deg<<<(N_EDGES + 255) / 256, 256, 0, stream>>>(edst, degi);
    k_scan<<<1, 1024, 0, stream>>>(degi, offs, cursor);
    k_scatter<<<(N_EDGES + 255) / 256, 256, 0, stream>>>(edst, esrc, cursor, srcp);
    k_xu_h1<<<N_NODES / 16, 256, 0, stream>>>(data, Wf, bx, degi, c, b_upd, xu, h1);
    k_ab<<<N_NODES / 16, 256, 0, stream>>>(h1, W_msg, b_msg, A, Bb);
    k_edge_h2<<<N_NODES / 16, 256, 0, stream>>>(offs, srcp, A, (const unsigned short*)Bb,
                                                r, h1, xu, W_upd, b_upd, ssum);
    k_out<<<1, 1024, 0, stream>>>(ssum, W_ro, b_ro, out);
}

// Round 7
// 180.764 us; speedup vs baseline: 1.4988x; 1.2316x over previous
//
#include <hip/hip_runtime.h>
#include <hip/hip_bf16.h>

#define N_NODES 20000
#define N_EDGES 320000
#define DATA_DIM 64
#define H 128

typedef __attribute__((ext_vector_type(8))) short bf16x8;
typedef __attribute__((ext_vector_type(4))) float f32x4;

__device__ __forceinline__ unsigned f2bbits(float x) { // fp32 -> bf16 bits (RNE)
    unsigned u = __float_as_uint(x);
    return (u + 0x7FFFu + ((u >> 16) & 1u)) >> 16;
}

// ---------- fused tiny precompute ----------
// blocks 0..63: Wf[d] = W_emb[d] @ Wu_x ; block 64: r, c, bx
__global__ void k_prewf(const float* __restrict__ W_emb,
                        const float* __restrict__ W_upd,
                        const float* __restrict__ b_emb,
                        const float* __restrict__ b_msg,
                        float* __restrict__ Wf, float* __restrict__ r,
                        float* __restrict__ c, float* __restrict__ bx) {
    int d = blockIdx.x;
    int j = threadIdx.x; // 128
    __shared__ float sh[H];
    if (d < DATA_DIM) {
        sh[j] = W_emb[d * H + j];
        __syncthreads();
        float acc = 0.f;
        for (int k = 0; k < H; k++)
            acc += sh[k] * W_upd[(256 + k) * H + j];
        Wf[d * H + j] = acc;
    } else {
        float rj = fmaxf(b_msg[j], 0.f);
        r[j] = rj;
        sh[j] = rj;
        __syncthreads();
        float cj = 0.f, bxj = 0.f;
        for (int k = 0; k < H; k++) {
            cj  += sh[k] * W_upd[k * H + j];            // Wu_m rows 0..127
            bxj += b_emb[k] * W_upd[(256 + k) * H + j]; // Wu_x rows 256..383
        }
        c[j] = cj;
        bx[j] = bxj;
    }
}

// ---------- swizzle weights into MFMA-fragment layout (bf16) ----------
// slot map (both operands, cancels in MFMA): k = kt*32 + (lane>>4)*8 + j, m/n = lane&15
// Wmsw: W' [k=128][n=256], n<128 -> W_msg[k][n] (dst), n>=128 -> W_msg[128+k][n-128] (src)
// Wusw: W_upd rows 0..255 [k=256][n=128]
__global__ void k_swz(const float* __restrict__ W_msg, const float* __restrict__ W_upd,
                      unsigned short* __restrict__ Wmsw, unsigned short* __restrict__ Wusw) {
    int id = blockIdx.x * 256 + threadIdx.x;
    if (id < 32768) {
        int k = id >> 8, n = id & 255;
        float src = (n < 128) ? W_msg[k * H + n] : W_msg[(128 + k) * H + (n - 128)];
        int kt = k >> 5, nt = n >> 4;
        int lane = ((k >> 3) & 3) * 16 + (n & 15), j = k & 7;
        Wmsw[(((kt * 16 + nt) * 64 + lane) << 3) + j] = (unsigned short)f2bbits(src);
    } else {
        int id2 = id - 32768;
        int k = id2 >> 7, n = id2 & 127;
        float src = W_upd[k * H + n];
        int kt = k >> 5, nt = n >> 4;
        int lane = ((k >> 3) & 3) * 16 + (n & 15), j = k & 7;
        Wusw[(((kt * 8 + nt) * 64 + lane) << 3) + j] = (unsigned short)f2bbits(src);
    }
}

// ---------- degree histogram over edge_dst ----------
__global__ void k_deg(const int* __restrict__ dst, int* __restrict__ deg) {
    int e = blockIdx.x * blockDim.x + threadIdx.x;
    if (e < N_EDGES) atomicAdd(&deg[dst[e]], 1);
}

// ---------- exclusive scan -> offs, cursor ----------
__global__ void k_scan(const int* __restrict__ deg, int* __restrict__ offs,
                       int* __restrict__ cursor) {
    __shared__ int buf[1024];
    int t = threadIdx.x;
    const int chunk = (N_NODES + 1023) / 1024; // 20
    int base = t * chunk;
    int s = 0;
    for (int i = 0; i < chunk; i++) {
        int idx = base + i;
        if (idx < N_NODES) s += deg[idx];
    }
    int val = s;
    for (int off = 1; off < 1024; off <<= 1) {
        buf[t] = val;
        __syncthreads();
        if (t >= off) val += buf[t - off];
        __syncthreads();
    }
    int run = val - s;
    for (int i = 0; i < chunk; i++) {
        int idx = base + i;
        if (idx < N_NODES) {
            offs[idx] = run;
            cursor[idx] = run;
            run += deg[idx];
        }
    }
    if (t == 1023) offs[N_NODES] = val;
}

// ---------- bucket-scatter SRC ids by dst ----------
__global__ void k_scatter(const int* __restrict__ dst, const int* __restrict__ src,
                          int* __restrict__ cursor, int* __restrict__ srcp) {
    int e = blockIdx.x * blockDim.x + threadIdx.x;
    if (e < N_EDGES) {
        int p = atomicAdd(&cursor[dst[e]], 1);
        srcp[p] = src[e];
    }
}

// ---------- xu = data @ Wf + bx ; h1 = tanh(deg*c + xu + b_upd) -> swizzled bf16 ----------
// thread: col pair (2p, 2p+1) x 4 nodes
__global__ void __launch_bounds__(256) k_xu_h1(
        const float* __restrict__ data, const float* __restrict__ Wf,
        const float* __restrict__ bx, const int* __restrict__ deg,
        const float* __restrict__ c, const float* __restrict__ b_upd,
        float* __restrict__ xu, unsigned int* __restrict__ h1sw) {
    __shared__ float ds[16][DATA_DIM]; // 4 KB
    int tid = threadIdx.x;
    int p = tid & 63, g = tid >> 6;
    int v0 = blockIdx.x * 16;
    for (int idx = tid; idx < 16 * DATA_DIM; idx += 256)
        ds[idx >> 6][idx & 63] = data[v0 * DATA_DIM + idx];
    __syncthreads();
    float ax[4] = {0, 0, 0, 0}, ay[4] = {0, 0, 0, 0};
    for (int k4 = 0; k4 < DATA_DIM; k4 += 4) {
        float4 xv[4];
        #pragma unroll
        for (int i = 0; i < 4; i++)
            xv[i] = *(const float4*)&ds[g * 4 + i][k4];
        #pragma unroll
        for (int q = 0; q < 4; q++) {
            float2 wv = *(const float2*)&Wf[(k4 + q) * H + 2 * p];
            #pragma unroll
            for (int i = 0; i < 4; i++) {
                float x = ((const float*)&xv[i])[q];
                ax[i] += x * wv.x;
                ay[i] += x * wv.y;
            }
        }
    }
    float2 bx2 = *(const float2*)&bx[2 * p];
    float2 c2  = *(const float2*)&c[2 * p];
    float2 bu2 = *(const float2*)&b_upd[2 * p];
    int vt = blockIdx.x;
    int kt = p >> 4, q16 = ((p >> 2) & 3) * 16, dw = p & 3;
    #pragma unroll
    for (int i = 0; i < 4; i++) {
        int v = v0 + g * 4 + i;
        float dvv = (float)deg[v];
        float x0 = ax[i] + bx2.x;
        float x1 = ay[i] + bx2.y;
        *(float2*)&xu[v * H + 2 * p] = make_float2(x0, x1);
        float h0 = tanhf(dvv * c2.x + x0 + bu2.x);
        float h1v = tanhf(dvv * c2.y + x1 + bu2.y);
        h1sw[(((vt * 4 + kt) * 64 + q16 + (v & 15)) << 2) + dw] =
            f2bbits(h0) | (f2bbits(h1v) << 16);
    }
}

// ---------- MFMA GEMM: [A'|Bb] = h1 @ [Wm_dst|Wm_src] (+b_msg on A') ----------
// wave = one 16-row m-tile; 16 n-tiles; k = 128 (4 k-steps)
__global__ void __launch_bounds__(256) k_ab(
        const unsigned short* __restrict__ h1sw,
        const unsigned short* __restrict__ Wmsw,
        const float* __restrict__ b_msg,
        float* __restrict__ A, unsigned short* __restrict__ Bb) {
    int tid = threadIdx.x;
    int lane = tid & 63, w = tid >> 6;
    int vt = blockIdx.x * 4 + w;
    if (vt >= N_NODES / 16) return;
    f32x4 acc[16];
    #pragma unroll
    for (int i = 0; i < 16; i++) acc[i] = (f32x4){0.f, 0.f, 0.f, 0.f};
    #pragma unroll
    for (int kt = 0; kt < 4; kt++) {
        bf16x8 af = *(const bf16x8*)(h1sw + (((vt * 4 + kt) * 64 + lane) << 3));
        #pragma unroll
        for (int nt = 0; nt < 16; nt++) {
            bf16x8 bfg = *(const bf16x8*)(Wmsw + (((kt * 16 + nt) * 64 + lane) << 3));
            acc[nt] = __builtin_amdgcn_mfma_f32_16x16x32_bf16(af, bfg, acc[nt], 0, 0, 0);
        }
    }
    int col = lane & 15, rg = lane >> 4;
    int vr = vt * 16 + rg * 4;
    #pragma unroll
    for (int nt = 0; nt < 8; nt++) {
        int n = nt * 16 + col;
        float bm = b_msg[n];
        #pragma unroll
        for (int i = 0; i < 4; i++)
            A[(vr + i) * H + n] = acc[nt][i] + bm;
    }
    #pragma unroll
    for (int nt = 8; nt < 16; nt++) {
        int n = (nt - 8) * 16 + col;
        #pragma unroll
        for (int i = 0; i < 4; i++)
            Bb[(vr + i) * H + n] = (unsigned short)f2bbits(acc[nt][i]);
    }
}

// ---------- fused: m2 (swizzled bf16 in LDS) = deg*r + sum_e relu(A'[v]+Bb[src]);
//            h2 = tanh([m2|h1]@Wu + xu + b_upd) via MFMA; col-sums -> atomic ssum ----------
__global__ void __launch_bounds__(256) k_edge_h2(
        const int* __restrict__ offs, const int* __restrict__ srcp,
        const float* __restrict__ A, const unsigned short* __restrict__ Bb,
        const float* __restrict__ r, const unsigned short* __restrict__ h1sw,
        const unsigned short* __restrict__ Wusw, const float* __restrict__ xu,
        const float* __restrict__ b_upd, float* __restrict__ ssum) {
    __shared__ unsigned int m2sw[4 * 64 * 4]; // 4 KB, fragment layout for 16x256 m2-tile
    int tid = threadIdx.x;
    int lane = tid & 63, w = tid >> 6;
    int vt = blockIdx.x;
    int v0 = vt * 16;
    // ---- edge phase: each wave owns 4 nodes; lane covers cols (2l, 2l+1) ----
    {
        const float2* r2 = (const float2*)r;
        float2 rr = r2[lane];
        for (int it = 0; it < 4; it++) {
            int n = w * 4 + it;
            int v = v0 + n;
            const float2* A2 = (const float2*)(A + v * H);
            float2 av = A2[lane];
            float t0 = av.x, t1 = av.y;
            int e0 = offs[v], e1 = offs[v + 1];
            float dv = (float)(e1 - e0);
            float acc0 = dv * rr.x, acc1 = dv * rr.y;
            while (e0 < e1) {
                int cnt = e1 - e0;
                if (cnt > 64) cnt = 64;
                int sv = (lane < cnt) ? srcp[e0 + lane] : 0;
                int i = 0;
                for (; i + 4 <= cnt; i += 4) {
                    int s0 = __builtin_amdgcn_readlane(sv, i);
                    int s1 = __builtin_amdgcn_readlane(sv, i + 1);
                    int s2 = __builtin_amdgcn_readlane(sv, i + 2);
                    int s3 = __builtin_amdgcn_readlane(sv, i + 3);
                    unsigned u0 = *(const unsigned*)(Bb + (size_t)s0 * H + 2 * lane);
                    unsigned u1 = *(const unsigned*)(Bb + (size_t)s1 * H + 2 * lane);
                    unsigned u2 = *(const unsigned*)(Bb + (size_t)s2 * H + 2 * lane);
                    unsigned u3 = *(const unsigned*)(Bb + (size_t)s3 * H + 2 * lane);
                    acc0 += fmaxf(t0 + __uint_as_float(u0 << 16), 0.f);
                    acc1 += fmaxf(t1 + __uint_as_float(u0 & 0xffff0000u), 0.f);
                    acc0 += fmaxf(t0 + __uint_as_float(u1 << 16), 0.f);
                    acc1 += fmaxf(t1 + __uint_as_float(u1 & 0xffff0000u), 0.f);
                    acc0 += fmaxf(t0 + __uint_as_float(u2 << 16), 0.f);
                    acc1 += fmaxf(t1 + __uint_as_float(u2 & 0xffff0000u), 0.f);
                    acc0 += fmaxf(t0 + __uint_as_float(u3 << 16), 0.f);
                    acc1 += fmaxf(t1 + __uint_as_float(u3 & 0xffff0000u), 0.f);
                }
                for (; i < cnt; i++) {
                    int s = __builtin_amdgcn_readlane(sv, i);
                    unsigned u = *(const unsigned*)(Bb + (size_t)s * H + 2 * lane);
                    acc0 += fmaxf(t0 + __uint_as_float(u << 16), 0.f);
                    acc1 += fmaxf(t1 + __uint_as_float(u & 0xffff0000u), 0.f);
                }
                e0 += cnt;
            }
            // swizzled bf16 write: cols (2l, 2l+1) of node n
            m2sw[(((lane >> 4) * 64 + ((lane >> 2) & 3) * 16 + n) << 2) + (lane & 3)] =
                f2bbits(acc0) | (f2bbits(acc1) << 16);
        }
    }
    __syncthreads();
    // ---- MFMA h2 phase: wave w -> n-tiles 2w, 2w+1; k = 256 (m2: kt 0..3, h1: kt 4..7) ----
    f32x4 acc[2];
    acc[0] = (f32x4){0.f, 0.f, 0.f, 0.f};
    acc[1] = (f32x4){0.f, 0.f, 0.f, 0.f};
    int nt0 = 2 * w;
    #pragma unroll
    for (int kt = 0; kt < 8; kt++) {
        bf16x8 af;
        if (kt < 4)
            af = *(const bf16x8*)&m2sw[(kt * 64 + lane) << 2];
        else
            af = *(const bf16x8*)(h1sw + (((vt * 4 + (kt - 4)) * 64 + lane) << 3));
        #pragma unroll
        for (int t = 0; t < 2; t++) {
            bf16x8 bfg = *(const bf16x8*)(Wusw + (((kt * 8 + nt0 + t) * 64 + lane) << 3));
            acc[t] = __builtin_amdgcn_mfma_f32_16x16x32_bf16(af, bfg, acc[t], 0, 0, 0);
        }
    }
    int col = lane & 15, rg = lane >> 4;
    #pragma unroll
    for (int t = 0; t < 2; t++) {
        int n = (nt0 + t) * 16 + col;
        float bu = b_upd[n];
        float s = 0.f;
        #pragma unroll
        for (int i = 0; i < 4; i++) {
            int v = v0 + rg * 4 + i;
            s += tanhf(acc[t][i] + xu[v * H + n] + bu);
        }
        s += __shfl_xor(s, 16);
        s += __shfl_xor(s, 32);
        if (rg == 0) atomicAdd(&ssum[n], s);
    }
}

// ---------- out = relu(ssum @ W_ro + b_ro), k-parallel ----------
__global__ void __launch_bounds__(1024) k_out(
        const float* __restrict__ ssum,
        const float* __restrict__ W_ro, const float* __restrict__ b_ro,
        float* __restrict__ out) {
    __shared__ float ss[H];
    __shared__ float red[8][H]; // 4 KB
    int tid = threadIdx.x;
    int j = tid & 127, g = tid >> 7; // 8 k-groups of 16
    if (tid < H) ss[tid] = ssum[tid];
    __syncthreads();
    float s = 0.f;
    #pragma unroll
    for (int q = 0; q < 16; q++) {
        int k = g * 16 + q;
        s += ss[k] * W_ro[k * H + j];
    }
    red[g][j] = s;
    __syncthreads();
    if (tid < H) {
        float acc = b_ro[tid];
        #pragma unroll
        for (int q = 0; q < 8; q++)
            acc += red[q][tid];
        out[tid] = fmaxf(acc, 0.f);
    }
}

extern "C" void kernel_launch(void* const* d_in, const int* in_sizes, int n_in,
                              void* d_out, int out_size, void* d_ws, size_t ws_size,
                              hipStream_t stream) {
    const float* data   = (const float*)d_in[0];
    const int*   esrc   = (const int*)d_in[1];
    const int*   edst   = (const int*)d_in[2];
    const float* W_emb  = (const float*)d_in[3];
    const float* b_emb  = (const float*)d_in[4];
    const float* W_msg  = (const float*)d_in[5];
    const float* b_msg  = (const float*)d_in[6];
    const float* W_upd  = (const float*)d_in[7];
    const float* b_upd  = (const float*)d_in[8];
    const float* W_ro   = (const float*)d_in[9];
    const float* b_ro   = (const float*)d_in[10];
    float* out = (float*)d_out;

    // workspace layout (16B-aligned chunks)
    float* xu    = (float*)d_ws;                 // N*H f32
    float* A     = xu + N_NODES * H;             // N*H f32
    unsigned short* h1sw = (unsigned short*)(A + N_NODES * H); // N*H bf16 (swizzled)
    unsigned short* Bb   = h1sw + N_NODES * H;   // N*H bf16 (linear)
    unsigned short* Wmsw = Bb + N_NODES * H;     // 32768 bf16
    unsigned short* Wusw = Wmsw + 32768;         // 32768 bf16
    float* ssum  = (float*)(Wusw + 32768);       // H
    float* r     = ssum + H;                     // H
    float* c     = r + H;                        // H
    float* bx    = c + H;                        // H
    float* Wf    = bx + H;                       // 64*H
    int* degi    = (int*)(Wf + DATA_DIM * H);    // N
    int* offs    = degi + N_NODES;               // N+1
    int* cursor  = offs + N_NODES + 1;           // N
    int* srcp    = cursor + N_NODES;             // E

    hipMemsetAsync(degi, 0, N_NODES * sizeof(int), stream);
    hipMemsetAsync(ssum, 0, H * sizeof(float), stream);

    k_prewf<<<DATA_DIM + 1, H, 0, stream>>>(W_emb, W_upd, b_emb, b_msg, Wf, r, c, bx);
    k_swz<<<256, 256, 0, stream>>>(W_msg, W_upd, Wmsw, Wusw);
    k_deg<<<(N_EDGES + 255) / 256, 256, 0, stream>>>(edst, degi);
    k_scan<<<1, 1024, 0, stream>>>(degi, offs, cursor);
    k_scatter<<<(N_EDGES + 255) / 256, 256, 0, stream>>>(edst, esrc, cursor, srcp);
    k_xu_h1<<<N_NODES / 16, 256, 0, stream>>>(data, Wf, bx, degi, c, b_upd,
                                              xu, (unsigned int*)h1sw);
    k_ab<<<(N_NODES / 16 + 3) / 4, 256, 0, stream>>>(h1sw, Wmsw, b_msg, A, Bb);
    k_edge_h2<<<N_NODES / 16, 256, 0, stream>>>(offs, srcp, A, Bb, r, h1sw,
                                                Wusw, xu, b_upd, ssum);
    k_out<<<1, 1024, 0, stream>>>(ssum, W_ro, b_ro, out);
}

// Round 8
// 169.846 us; speedup vs baseline: 1.5951x; 1.0643x over previous
//
#include <hip/hip_runtime.h>
#include <hip/hip_bf16.h>

#define N_NODES 20000
#define N_EDGES 320000
#define DATA_DIM 64
#define H 128
#define NVT (N_NODES / 16)   // 1250 node tiles

typedef __attribute__((ext_vector_type(8))) short bf16x8;
typedef __attribute__((ext_vector_type(4))) float f32x4;

__device__ __forceinline__ unsigned f2bbits(float x) { // fp32 -> bf16 bits (RNE)
    unsigned u = __float_as_uint(x);
    return (u + 0x7FFFu + ((u >> 16) & 1u)) >> 16;
}

// ---------- fused tiny precompute ----------
// blocks 0..63: Wf[d] = W_emb[d] @ Wu_x (also swizzled bf16) ; block 64: r, c, bx
__global__ void k_prewf(const float* __restrict__ W_emb,
                        const float* __restrict__ W_upd,
                        const float* __restrict__ b_emb,
                        const float* __restrict__ b_msg,
                        float* __restrict__ Wf, unsigned short* __restrict__ Wfsw,
                        float* __restrict__ r,
                        float* __restrict__ c, float* __restrict__ bx) {
    int d = blockIdx.x;
    int j = threadIdx.x; // 128
    __shared__ float sh[H];
    if (d < DATA_DIM) {
        sh[j] = W_emb[d * H + j];
        __syncthreads();
        float acc = 0.f;
        for (int k = 0; k < H; k++)
            acc += sh[k] * W_upd[(256 + k) * H + j];
        Wf[d * H + j] = acc;
        // swizzled bf16 copy: element (k=d, n=j)
        int kt = d >> 5, lane2 = ((d >> 3) & 3) * 16 + (j & 15), jj = d & 7;
        Wfsw[(((kt * 8 + (j >> 4)) * 64 + lane2) << 3) + jj] = (unsigned short)f2bbits(acc);
    } else {
        float rj = fmaxf(b_msg[j], 0.f);
        r[j] = rj;
        sh[j] = rj;
        __syncthreads();
        float cj = 0.f, bxj = 0.f;
        for (int k = 0; k < H; k++) {
            cj  += sh[k] * W_upd[k * H + j];            // Wu_m rows 0..127
            bxj += b_emb[k] * W_upd[(256 + k) * H + j]; // Wu_x rows 256..383
        }
        c[j] = cj;
        bx[j] = bxj;
    }
}

// ---------- swizzle weights + data into MFMA-fragment layout (bf16) ----------
// slot map (cancels between A and B in MFMA): k = kt*32 + (lane>>4)*8 + j, m/n = lane&15
__global__ void k_swz(const float* __restrict__ W_msg, const float* __restrict__ W_upd,
                      const float* __restrict__ data,
                      unsigned short* __restrict__ Wmsw, unsigned short* __restrict__ Wusw,
                      unsigned int* __restrict__ data_sw) {
    int gid = blockIdx.x * 256 + threadIdx.x;
    if (gid < 32768) {
        int k = gid >> 8, n = gid & 255;
        float src = (n < 128) ? W_msg[k * H + n] : W_msg[(128 + k) * H + (n - 128)];
        int kt = k >> 5, nt = n >> 4;
        int lane = ((k >> 3) & 3) * 16 + (n & 15), j = k & 7;
        Wmsw[(((kt * 16 + nt) * 64 + lane) << 3) + j] = (unsigned short)f2bbits(src);
    } else if (gid < 65536) {
        int id2 = gid - 32768;
        int k = id2 >> 7, n = id2 & 127;
        float src = W_upd[k * H + n];
        int kt = k >> 5, nt = n >> 4;
        int lane = ((k >> 3) & 3) * 16 + (n & 15), j = k & 7;
        Wusw[(((kt * 8 + nt) * 64 + lane) << 3) + j] = (unsigned short)f2bbits(src);
    } else {
        int id = gid - 65536;            // [0, 20000*32)
        if (id >= N_NODES * 32) return;
        int v = id >> 5, k = (id & 31) * 2;
        float2 dv = *(const float2*)(data + v * DATA_DIM + k);
        int vt = v >> 4, rr = v & 15;
        int kt = k >> 5;
        int lane2 = ((k >> 3) & 3) * 16 + rr, j = k & 7;
        data_sw[(((vt * 2 + kt) * 64 + lane2) << 2) + (j >> 1)] =
            f2bbits(dv.x) | (f2bbits(dv.y) << 16);
    }
}

// ---------- degree histogram over edge_dst ----------
__global__ void k_deg(const int* __restrict__ dst, int* __restrict__ deg) {
    int e = blockIdx.x * blockDim.x + threadIdx.x;
    if (e < N_EDGES) atomicAdd(&deg[dst[e]], 1);
}

// ---------- exclusive scan -> offs, cursor ----------
__global__ void k_scan(const int* __restrict__ deg, int* __restrict__ offs,
                       int* __restrict__ cursor) {
    __shared__ int buf[1024];
    int t = threadIdx.x;
    const int chunk = (N_NODES + 1023) / 1024; // 20
    int base = t * chunk;
    int s = 0;
    for (int i = 0; i < chunk; i++) {
        int idx = base + i;
        if (idx < N_NODES) s += deg[idx];
    }
    int val = s;
    for (int off = 1; off < 1024; off <<= 1) {
        buf[t] = val;
        __syncthreads();
        if (t >= off) val += buf[t - off];
        __syncthreads();
    }
    int run = val - s;
    for (int i = 0; i < chunk; i++) {
        int idx = base + i;
        if (idx < N_NODES) {
            offs[idx] = run;
            cursor[idx] = run;
            run += deg[idx];
        }
    }
    if (t == 1023) offs[N_NODES] = val;
}

// ---------- bucket-scatter SRC ids by dst ----------
__global__ void k_scatter(const int* __restrict__ dst, const int* __restrict__ src,
                          int* __restrict__ cursor, int* __restrict__ srcp) {
    int e = blockIdx.x * blockDim.x + threadIdx.x;
    if (e < N_EDGES) {
        int p = atomicAdd(&cursor[dst[e]], 1);
        srcp[p] = src[e];
    }
}

// ---------- MFMA: xu = data @ Wf + bx ; h1 = tanh(deg*c + xu + b_upd) -> h1sw ----------
// wave = one 16-node tile; K=64 (2 kt); 8 n-tiles
__global__ void __launch_bounds__(256) k_xu_h1(
        const unsigned short* __restrict__ data_sw,
        const unsigned short* __restrict__ Wfsw,
        const float* __restrict__ bx, const int* __restrict__ offs,
        const float* __restrict__ c, const float* __restrict__ b_upd,
        float* __restrict__ xu, unsigned short* __restrict__ h1sw) {
    int tid = threadIdx.x;
    int lane = tid & 63, w = tid >> 6;
    int vt = blockIdx.x * 4 + w;
    if (vt >= NVT) return;
    f32x4 acc[8];
    #pragma unroll
    for (int i = 0; i < 8; i++) acc[i] = (f32x4){0.f, 0.f, 0.f, 0.f};
    #pragma unroll
    for (int kt = 0; kt < 2; kt++) {
        bf16x8 af = *(const bf16x8*)(data_sw + (((vt * 2 + kt) * 64 + lane) << 3));
        #pragma unroll
        for (int nt = 0; nt < 8; nt++) {
            bf16x8 bfg = *(const bf16x8*)(Wfsw + (((kt * 8 + nt) * 64 + lane) << 3));
            acc[nt] = __builtin_amdgcn_mfma_f32_16x16x32_bf16(af, bfg, acc[nt], 0, 0, 0);
        }
    }
    int col = lane & 15, rg = lane >> 4;
    int v0 = vt * 16;
    float dvv[4];
    #pragma unroll
    for (int i = 0; i < 4; i++) {
        int v = v0 + rg * 4 + i;
        dvv[i] = (float)(offs[v + 1] - offs[v]);
    }
    #pragma unroll
    for (int nt = 0; nt < 8; nt++) {
        int n = nt * 16 + col;
        float bxn = bx[n], cn = c[n], bun = b_upd[n];
        int kt2 = n >> 5, lane2b = ((n >> 3) & 3) * 16, j2 = n & 7;
        #pragma unroll
        for (int i = 0; i < 4; i++) {
            int rr = rg * 4 + i;
            float xv = acc[nt][i] + bxn;
            xu[(v0 + rr) * H + n] = xv;
            float hh = tanhf(dvv[i] * cn + xv + bun);
            h1sw[(((vt * 4 + kt2) * 64 + lane2b + rr) << 3) + j2] =
                (unsigned short)f2bbits(hh);
        }
    }
}

// ---------- MFMA GEMM: [A'|Bb] = h1 @ [Wm_dst|Wm_src] (+b_msg on A') ----------
__global__ void __launch_bounds__(256) k_ab(
        const unsigned short* __restrict__ h1sw,
        const unsigned short* __restrict__ Wmsw,
        const float* __restrict__ b_msg,
        float* __restrict__ A, unsigned short* __restrict__ Bb) {
    int tid = threadIdx.x;
    int lane = tid & 63, w = tid >> 6;
    int vt = blockIdx.x * 4 + w;
    if (vt >= NVT) return;
    f32x4 acc[16];
    #pragma unroll
    for (int i = 0; i < 16; i++) acc[i] = (f32x4){0.f, 0.f, 0.f, 0.f};
    #pragma unroll
    for (int kt = 0; kt < 4; kt++) {
        bf16x8 af = *(const bf16x8*)(h1sw + (((vt * 4 + kt) * 64 + lane) << 3));
        #pragma unroll
        for (int nt = 0; nt < 16; nt++) {
            bf16x8 bfg = *(const bf16x8*)(Wmsw + (((kt * 16 + nt) * 64 + lane) << 3));
            acc[nt] = __builtin_amdgcn_mfma_f32_16x16x32_bf16(af, bfg, acc[nt], 0, 0, 0);
        }
    }
    int col = lane & 15, rg = lane >> 4;
    int vr = vt * 16 + rg * 4;
    #pragma unroll
    for (int nt = 0; nt < 8; nt++) {
        int n = nt * 16 + col;
        float bm = b_msg[n];
        #pragma unroll
        for (int i = 0; i < 4; i++)
            A[(vr + i) * H + n] = acc[nt][i] + bm;
    }
    #pragma unroll
    for (int nt = 8; nt < 16; nt++) {
        int n = (nt - 8) * 16 + col;
        #pragma unroll
        for (int i = 0; i < 4; i++)
            Bb[(vr + i) * H + n] = (unsigned short)f2bbits(acc[nt][i]);
    }
}

// ---------- edge reduce: one node per wave; m2 -> swizzled bf16 in GLOBAL ----------
// m2[v] = deg*r + sum_e relu(A'[v] + Bb[src]); lane covers cols (2l, 2l+1)
__global__ void __launch_bounds__(256) k_edge(
        const int* __restrict__ offs, const int* __restrict__ srcp,
        const float* __restrict__ A, const unsigned short* __restrict__ Bb,
        const float* __restrict__ r, unsigned int* __restrict__ m2sw) {
    int tid = threadIdx.x;
    int lane = tid & 63, w = tid >> 6;
    int v = blockIdx.x * 4 + w;
    if (v >= N_NODES) return;
    const float2* r2 = (const float2*)r;
    float2 rr = r2[lane];
    const float2* A2 = (const float2*)(A + (size_t)v * H);
    float2 av = A2[lane];
    float t0 = av.x, t1 = av.y;
    int e0 = offs[v], e1 = offs[v + 1];
    float dv = (float)(e1 - e0);
    float acc0 = dv * rr.x, acc1 = dv * rr.y;
    while (e0 < e1) {
        int cnt = e1 - e0;
        if (cnt > 64) cnt = 64;
        int sv = (lane < cnt) ? srcp[e0 + lane] : 0;
        int i = 0;
        for (; i + 4 <= cnt; i += 4) {
            int s0 = __builtin_amdgcn_readlane(sv, i);
            int s1 = __builtin_amdgcn_readlane(sv, i + 1);
            int s2 = __builtin_amdgcn_readlane(sv, i + 2);
            int s3 = __builtin_amdgcn_readlane(sv, i + 3);
            unsigned u0 = *(const unsigned*)(Bb + (size_t)s0 * H + 2 * lane);
            unsigned u1 = *(const unsigned*)(Bb + (size_t)s1 * H + 2 * lane);
            unsigned u2 = *(const unsigned*)(Bb + (size_t)s2 * H + 2 * lane);
            unsigned u3 = *(const unsigned*)(Bb + (size_t)s3 * H + 2 * lane);
            acc0 += fmaxf(t0 + __uint_as_float(u0 << 16), 0.f);
            acc1 += fmaxf(t1 + __uint_as_float(u0 & 0xffff0000u), 0.f);
            acc0 += fmaxf(t0 + __uint_as_float(u1 << 16), 0.f);
            acc1 += fmaxf(t1 + __uint_as_float(u1 & 0xffff0000u), 0.f);
            acc0 += fmaxf(t0 + __uint_as_float(u2 << 16), 0.f);
            acc1 += fmaxf(t1 + __uint_as_float(u2 & 0xffff0000u), 0.f);
            acc0 += fmaxf(t0 + __uint_as_float(u3 << 16), 0.f);
            acc1 += fmaxf(t1 + __uint_as_float(u3 & 0xffff0000u), 0.f);
        }
        for (; i < cnt; i++) {
            int s = __builtin_amdgcn_readlane(sv, i);
            unsigned u = *(const unsigned*)(Bb + (size_t)s * H + 2 * lane);
            acc0 += fmaxf(t0 + __uint_as_float(u << 16), 0.f);
            acc1 += fmaxf(t1 + __uint_as_float(u & 0xffff0000u), 0.f);
        }
        e0 += cnt;
    }
    // swizzled bf16 store of cols (2l, 2l+1) for node v
    int vt = v >> 4, n = v & 15;
    int kt = lane >> 4;
    int lane2 = ((lane >> 2) & 3) * 16 + n;
    m2sw[(((vt * 4 + kt) * 64 + lane2) << 2) + (lane & 3)] =
        f2bbits(acc0) | (f2bbits(acc1) << 16);
}

// ---------- MFMA: h2 = tanh([m2|h1]@Wu + xu + b_upd); col-sums -> atomic ssum ----------
// wave w -> n-tiles 2w, 2w+1; k = 256 (m2sw: kt 0..3, h1sw: kt 4..7)
__global__ void __launch_bounds__(256) k_h2(
        const unsigned short* __restrict__ m2sw,
        const unsigned short* __restrict__ h1sw,
        const unsigned short* __restrict__ Wusw, const float* __restrict__ xu,
        const float* __restrict__ b_upd, float* __restrict__ ssum) {
    int tid = threadIdx.x;
    int lane = tid & 63, w = tid >> 6;
    int vt = blockIdx.x;
    int v0 = vt * 16;
    f32x4 acc[2];
    acc[0] = (f32x4){0.f, 0.f, 0.f, 0.f};
    acc[1] = (f32x4){0.f, 0.f, 0.f, 0.f};
    int nt0 = 2 * w;
    #pragma unroll
    for (int kt = 0; kt < 8; kt++) {
        bf16x8 af;
        if (kt < 4)
            af = *(const bf16x8*)(m2sw + (((vt * 4 + kt) * 64 + lane) << 3));
        else
            af = *(const bf16x8*)(h1sw + (((vt * 4 + (kt - 4)) * 64 + lane) << 3));
        #pragma unroll
        for (int t = 0; t < 2; t++) {
            bf16x8 bfg = *(const bf16x8*)(Wusw + (((kt * 8 + nt0 + t) * 64 + lane) << 3));
            acc[t] = __builtin_amdgcn_mfma_f32_16x16x32_bf16(af, bfg, acc[t], 0, 0, 0);
        }
    }
    int col = lane & 15, rg = lane >> 4;
    #pragma unroll
    for (int t = 0; t < 2; t++) {
        int n = (nt0 + t) * 16 + col;
        float bu = b_upd[n];
        float s = 0.f;
        #pragma unroll
        for (int i = 0; i < 4; i++) {
            int v = v0 + rg * 4 + i;
            s += tanhf(acc[t][i] + xu[v * H + n] + bu);
        }
        s += __shfl_xor(s, 16);
        s += __shfl_xor(s, 32);
        if (rg == 0) atomicAdd(&ssum[n], s);
    }
}

// ---------- out = relu(ssum @ W_ro + b_ro), k-parallel ----------
__global__ void __launch_bounds__(1024) k_out(
        const float* __restrict__ ssum,
        const float* __restrict__ W_ro, const float* __restrict__ b_ro,
        float* __restrict__ out) {
    __shared__ float ss[H];
    __shared__ float red[8][H]; // 4 KB
    int tid = threadIdx.x;
    int j = tid & 127, g = tid >> 7; // 8 k-groups of 16
    if (tid < H) ss[tid] = ssum[tid];
    __syncthreads();
    float s = 0.f;
    #pragma unroll
    for (int q = 0; q < 16; q++) {
        int k = g * 16 + q;
        s += ss[k] * W_ro[k * H + j];
    }
    red[g][j] = s;
    __syncthreads();
    if (tid < H) {
        float acc = b_ro[tid];
        #pragma unroll
        for (int q = 0; q < 8; q++)
            acc += red[q][tid];
        out[tid] = fmaxf(acc, 0.f);
    }
}

extern "C" void kernel_launch(void* const* d_in, const int* in_sizes, int n_in,
                              void* d_out, int out_size, void* d_ws, size_t ws_size,
                              hipStream_t stream) {
    const float* data   = (const float*)d_in[0];
    const int*   esrc   = (const int*)d_in[1];
    const int*   edst   = (const int*)d_in[2];
    const float* W_emb  = (const float*)d_in[3];
    const float* b_emb  = (const float*)d_in[4];
    const float* W_msg  = (const float*)d_in[5];
    const float* b_msg  = (const float*)d_in[6];
    const float* W_upd  = (const float*)d_in[7];
    const float* b_upd  = (const float*)d_in[8];
    const float* W_ro   = (const float*)d_in[9];
    const float* b_ro   = (const float*)d_in[10];
    float* out = (float*)d_out;

    // workspace layout (16B-aligned chunks)
    float* xu    = (float*)d_ws;                 // N*H f32
    float* A     = xu + N_NODES * H;             // N*H f32
    unsigned short* h1sw = (unsigned short*)(A + N_NODES * H); // N*H bf16 (swizzled)
    unsigned short* Bb   = h1sw + N_NODES * H;   // N*H bf16 (linear)
    unsigned short* m2sw = Bb + N_NODES * H;     // N*H bf16 (swizzled)
    unsigned short* dsw  = m2sw + N_NODES * H;   // N*DATA_DIM bf16 (swizzled)
    unsigned short* Wmsw = dsw + N_NODES * DATA_DIM; // 32768 bf16
    unsigned short* Wusw = Wmsw + 32768;         // 32768 bf16
    unsigned short* Wfsw = Wusw + 32768;         // 8192 bf16
    float* ssum  = (float*)(Wfsw + 8192);        // H
    float* r     = ssum + H;                     // H
    float* c     = r + H;                        // H
    float* bx    = c + H;                        // H
    float* Wf    = bx + H;                       // 64*H
    int* degi    = (int*)(Wf + DATA_DIM * H);    // N
    int* offs    = degi + N_NODES;               // N+1
    int* cursor  = offs + N_NODES + 1;           // N
    int* srcp    = cursor + N_NODES;             // E

    hipMemsetAsync(degi, 0, N_NODES * sizeof(int), stream);
    hipMemsetAsync(ssum, 0, H * sizeof(float), stream);

    k_prewf<<<DATA_DIM + 1, H, 0, stream>>>(W_emb, W_upd, b_emb, b_msg,
                                            Wf, Wfsw, r, c, bx);
    k_swz<<<(65536 + N_NODES * 32 + 255) / 256, 256, 0, stream>>>(
        W_msg, W_upd, data, Wmsw, Wusw, (unsigned int*)dsw);
    k_deg<<<(N_EDGES + 255) / 256, 256, 0, stream>>>(edst, degi);
    k_scan<<<1, 1024, 0, stream>>>(degi, offs, cursor);
    k_scatter<<<(N_EDGES + 255) / 256, 256, 0, stream>>>(edst, esrc, cursor, srcp);
    k_xu_h1<<<(NVT + 3) / 4, 256, 0, stream>>>(dsw, Wfsw, bx, offs, c, b_upd,
                                               xu, h1sw);
    k_ab<<<(NVT + 3) / 4, 256, 0, stream>>>(h1sw, Wmsw, b_msg, A, Bb);
    k_edge<<<N_NODES / 4, 256, 0, stream>>>(offs, srcp, A, Bb, r,
                                            (unsigned int*)m2sw);
    k_h2<<<NVT, 256, 0, stream>>>(m2sw, h1sw, Wusw, xu, b_upd, ssum);
    k_out<<<1, 1024, 0, stream>>>(ssum, W_ro, b_ro, out);
}

// Round 9
// 159.178 us; speedup vs baseline: 1.7021x; 1.0670x over previous
//
#include <hip/hip_runtime.h>
#include <hip/hip_bf16.h>

#define N_NODES 20000
#define N_EDGES 320000
#define DATA_DIM 64
#define H 128
#define NVT (N_NODES / 16)   // 1250 node tiles

// k_pre block ranges
#define DSW_END   (65536 + N_NODES * 32)          // 705536
#define DEG_END   (DSW_END + N_NODES)             // 725536
#define SWZ_BLOCKS ((DEG_END + 255) / 256)        // 2835
#define PRE_BLOCKS (SWZ_BLOCKS + DATA_DIM + 1)    // +65

typedef __attribute__((ext_vector_type(8))) short bf16x8;
typedef __attribute__((ext_vector_type(4))) float f32x4;

__device__ __forceinline__ unsigned f2bbits(float x) { // fp32 -> bf16 bits (RNE)
    unsigned u = __float_as_uint(x);
    return (u + 0x7FFFu + ((u >> 16) & 1u)) >> 16;
}

// ---------- mega-precompute: weight/data swizzles + Wf + r/c/bx + degi zero ----------
// slot map (cancels between A and B operands in MFMA): k = kt*32+(lane>>4)*8+j, m/n = lane&15
__global__ void k_pre(const float* __restrict__ W_emb, const float* __restrict__ W_upd,
                      const float* __restrict__ b_emb, const float* __restrict__ b_msg,
                      const float* __restrict__ W_msg, const float* __restrict__ data,
                      float* __restrict__ Wf, unsigned short* __restrict__ Wfsw,
                      float* __restrict__ r, float* __restrict__ c, float* __restrict__ bx,
                      unsigned short* __restrict__ Wmsw, unsigned short* __restrict__ Wusw,
                      unsigned int* __restrict__ data_sw, int* __restrict__ deg) {
    int tid = threadIdx.x;
    __shared__ float sh[H];
    if (blockIdx.x >= SWZ_BLOCKS) {
        // ---- prewf part: blocks SWZ_BLOCKS .. SWZ_BLOCKS+64 ----
        int d = blockIdx.x - SWZ_BLOCKS;
        int j = tid & 127;
        bool lo = tid < 128;
        if (d < DATA_DIM) {
            if (lo) sh[j] = W_emb[d * H + j];
            __syncthreads();
            if (lo) {
                float acc = 0.f;
                for (int k = 0; k < H; k++)
                    acc += sh[k] * W_upd[(256 + k) * H + j];
                Wf[d * H + j] = acc;
                int kt = d >> 5, lane2 = ((d >> 3) & 3) * 16 + (j & 15), jj = d & 7;
                Wfsw[(((kt * 8 + (j >> 4)) * 64 + lane2) << 3) + jj] =
                    (unsigned short)f2bbits(acc);
            }
        } else {
            if (lo) {
                float rj = fmaxf(b_msg[j], 0.f);
                r[j] = rj;
                sh[j] = rj;
            }
            __syncthreads();
            if (lo) {
                float cj = 0.f, bxj = 0.f;
                for (int k = 0; k < H; k++) {
                    cj  += sh[k] * W_upd[k * H + j];            // Wu_m rows 0..127
                    bxj += b_emb[k] * W_upd[(256 + k) * H + j]; // Wu_x rows 256..383
                }
                c[j] = cj;
                bx[j] = bxj;
            }
        }
        return;
    }
    int gid = blockIdx.x * 256 + tid;
    if (gid < 32768) {
        int k = gid >> 8, n = gid & 255;
        float src = (n < 128) ? W_msg[k * H + n] : W_msg[(128 + k) * H + (n - 128)];
        int kt = k >> 5, nt = n >> 4;
        int lane = ((k >> 3) & 3) * 16 + (n & 15), j = k & 7;
        Wmsw[(((kt * 16 + nt) * 64 + lane) << 3) + j] = (unsigned short)f2bbits(src);
    } else if (gid < 65536) {
        int id2 = gid - 32768;
        int k = id2 >> 7, n = id2 & 127;
        float src = W_upd[k * H + n];
        int kt = k >> 5, nt = n >> 4;
        int lane = ((k >> 3) & 3) * 16 + (n & 15), j = k & 7;
        Wusw[(((kt * 8 + nt) * 64 + lane) << 3) + j] = (unsigned short)f2bbits(src);
    } else if (gid < DSW_END) {
        int id = gid - 65536;            // [0, N_NODES*32)
        int v = id >> 5, k = (id & 31) * 2;
        float2 dv = *(const float2*)(data + v * DATA_DIM + k);
        int vt = v >> 4, rr = v & 15;
        int kt = k >> 5;
        int lane2 = ((k >> 3) & 3) * 16 + rr, j = k & 7;
        data_sw[(((vt * 2 + kt) * 64 + lane2) << 2) + (j >> 1)] =
            f2bbits(dv.x) | (f2bbits(dv.y) << 16);
    } else if (gid < DEG_END) {
        deg[gid - DSW_END] = 0;
    }
}

// ---------- degree histogram over edge_dst ----------
__global__ void k_deg(const int* __restrict__ dst, int* __restrict__ deg) {
    int e = blockIdx.x * blockDim.x + threadIdx.x;
    if (e < N_EDGES) atomicAdd(&deg[dst[e]], 1);
}

// ---------- exclusive scan -> offs, cursor (also zeroes ssum) ----------
__global__ void k_scan(const int* __restrict__ deg, int* __restrict__ offs,
                       int* __restrict__ cursor, float* __restrict__ ssum) {
    __shared__ int buf[1024];
    int t = threadIdx.x;
    if (t < H) ssum[t] = 0.f;
    const int chunk = (N_NODES + 1023) / 1024; // 20
    int base = t * chunk;
    int s = 0;
    for (int i = 0; i < chunk; i++) {
        int idx = base + i;
        if (idx < N_NODES) s += deg[idx];
    }
    int val = s;
    for (int off = 1; off < 1024; off <<= 1) {
        buf[t] = val;
        __syncthreads();
        if (t >= off) val += buf[t - off];
        __syncthreads();
    }
    int run = val - s;
    for (int i = 0; i < chunk; i++) {
        int idx = base + i;
        if (idx < N_NODES) {
            offs[idx] = run;
            cursor[idx] = run;
            run += deg[idx];
        }
    }
    if (t == 1023) offs[N_NODES] = val;
}

// ---------- bucket-scatter SRC ids by dst ----------
__global__ void k_scatter(const int* __restrict__ dst, const int* __restrict__ src,
                          int* __restrict__ cursor, int* __restrict__ srcp) {
    int e = blockIdx.x * blockDim.x + threadIdx.x;
    if (e < N_EDGES) {
        int p = atomicAdd(&cursor[dst[e]], 1);
        srcp[p] = src[e];
    }
}

// ---------- MFMA: xu = data @ Wf + bx ; h1 = tanh(deg*c + xu + b_upd) -> h1sw ----------
__global__ void __launch_bounds__(256) k_xu_h1(
        const unsigned short* __restrict__ data_sw,
        const unsigned short* __restrict__ Wfsw,
        const float* __restrict__ bx, const int* __restrict__ offs,
        const float* __restrict__ c, const float* __restrict__ b_upd,
        float* __restrict__ xu, unsigned short* __restrict__ h1sw) {
    int tid = threadIdx.x;
    int lane = tid & 63, w = tid >> 6;
    int vt = blockIdx.x * 4 + w;
    if (vt >= NVT) return;
    f32x4 acc[8];
    #pragma unroll
    for (int i = 0; i < 8; i++) acc[i] = (f32x4){0.f, 0.f, 0.f, 0.f};
    #pragma unroll
    for (int kt = 0; kt < 2; kt++) {
        bf16x8 af = *(const bf16x8*)(data_sw + (((vt * 2 + kt) * 64 + lane) << 3));
        #pragma unroll
        for (int nt = 0; nt < 8; nt++) {
            bf16x8 bfg = *(const bf16x8*)(Wfsw + (((kt * 8 + nt) * 64 + lane) << 3));
            acc[nt] = __builtin_amdgcn_mfma_f32_16x16x32_bf16(af, bfg, acc[nt], 0, 0, 0);
        }
    }
    int col = lane & 15, rg = lane >> 4;
    int v0 = vt * 16;
    float dvv[4];
    #pragma unroll
    for (int i = 0; i < 4; i++) {
        int v = v0 + rg * 4 + i;
        dvv[i] = (float)(offs[v + 1] - offs[v]);
    }
    #pragma unroll
    for (int nt = 0; nt < 8; nt++) {
        int n = nt * 16 + col;
        float bxn = bx[n], cn = c[n], bun = b_upd[n];
        int kt2 = n >> 5, lane2b = ((n >> 3) & 3) * 16, j2 = n & 7;
        #pragma unroll
        for (int i = 0; i < 4; i++) {
            int rr = rg * 4 + i;
            float xv = acc[nt][i] + bxn;
            xu[(v0 + rr) * H + n] = xv;
            float hh = tanhf(dvv[i] * cn + xv + bun);
            h1sw[(((vt * 4 + kt2) * 64 + lane2b + rr) << 3) + j2] =
                (unsigned short)f2bbits(hh);
        }
    }
}

// ---------- MFMA GEMM: [A'|Bb] = h1 @ [Wm_dst|Wm_src] (+b_msg on A') ----------
__global__ void __launch_bounds__(256) k_ab(
        const unsigned short* __restrict__ h1sw,
        const unsigned short* __restrict__ Wmsw,
        const float* __restrict__ b_msg,
        float* __restrict__ A, unsigned short* __restrict__ Bb) {
    int tid = threadIdx.x;
    int lane = tid & 63, w = tid >> 6;
    int vt = blockIdx.x * 4 + w;
    if (vt >= NVT) return;
    f32x4 acc[16];
    #pragma unroll
    for (int i = 0; i < 16; i++) acc[i] = (f32x4){0.f, 0.f, 0.f, 0.f};
    #pragma unroll
    for (int kt = 0; kt < 4; kt++) {
        bf16x8 af = *(const bf16x8*)(h1sw + (((vt * 4 + kt) * 64 + lane) << 3));
        #pragma unroll
        for (int nt = 0; nt < 16; nt++) {
            bf16x8 bfg = *(const bf16x8*)(Wmsw + (((kt * 16 + nt) * 64 + lane) << 3));
            acc[nt] = __builtin_amdgcn_mfma_f32_16x16x32_bf16(af, bfg, acc[nt], 0, 0, 0);
        }
    }
    int col = lane & 15, rg = lane >> 4;
    int vr = vt * 16 + rg * 4;
    #pragma unroll
    for (int nt = 0; nt < 8; nt++) {
        int n = nt * 16 + col;
        float bm = b_msg[n];
        #pragma unroll
        for (int i = 0; i < 4; i++)
            A[(vr + i) * H + n] = acc[nt][i] + bm;
    }
    #pragma unroll
    for (int nt = 8; nt < 16; nt++) {
        int n = (nt - 8) * 16 + col;
        #pragma unroll
        for (int i = 0; i < 4; i++)
            Bb[(vr + i) * H + n] = (unsigned short)f2bbits(acc[nt][i]);
    }
}

// ---------- edge reduce: one node per wave; unroll-8 gather; m2 -> swizzled bf16 global ----------
__global__ void __launch_bounds__(256) k_edge(
        const int* __restrict__ offs, const int* __restrict__ srcp,
        const float* __restrict__ A, const unsigned short* __restrict__ Bb,
        const float* __restrict__ r, unsigned int* __restrict__ m2sw) {
    int tid = threadIdx.x;
    int lane = tid & 63, w = tid >> 6;
    int v = blockIdx.x * 4 + w;
    if (v >= N_NODES) return;
    const float2* r2 = (const float2*)r;
    float2 rr = r2[lane];
    const float2* A2 = (const float2*)(A + (size_t)v * H);
    float2 av = A2[lane];
    float t0 = av.x, t1 = av.y;
    int e0 = offs[v], e1 = offs[v + 1];
    float dv = (float)(e1 - e0);
    float acc0 = dv * rr.x, acc1 = dv * rr.y;
    while (e0 < e1) {
        int cnt = e1 - e0;
        if (cnt > 64) cnt = 64;
        int sv = (lane < cnt) ? srcp[e0 + lane] : 0;
        int i = 0;
        for (; i + 8 <= cnt; i += 8) {
            int s0 = __builtin_amdgcn_readlane(sv, i);
            int s1 = __builtin_amdgcn_readlane(sv, i + 1);
            int s2 = __builtin_amdgcn_readlane(sv, i + 2);
            int s3 = __builtin_amdgcn_readlane(sv, i + 3);
            int s4 = __builtin_amdgcn_readlane(sv, i + 4);
            int s5 = __builtin_amdgcn_readlane(sv, i + 5);
            int s6 = __builtin_amdgcn_readlane(sv, i + 6);
            int s7 = __builtin_amdgcn_readlane(sv, i + 7);
            unsigned u0 = *(const unsigned*)(Bb + (size_t)s0 * H + 2 * lane);
            unsigned u1 = *(const unsigned*)(Bb + (size_t)s1 * H + 2 * lane);
            unsigned u2 = *(const unsigned*)(Bb + (size_t)s2 * H + 2 * lane);
            unsigned u3 = *(const unsigned*)(Bb + (size_t)s3 * H + 2 * lane);
            unsigned u4 = *(const unsigned*)(Bb + (size_t)s4 * H + 2 * lane);
            unsigned u5 = *(const unsigned*)(Bb + (size_t)s5 * H + 2 * lane);
            unsigned u6 = *(const unsigned*)(Bb + (size_t)s6 * H + 2 * lane);
            unsigned u7 = *(const unsigned*)(Bb + (size_t)s7 * H + 2 * lane);
            acc0 += fmaxf(t0 + __uint_as_float(u0 << 16), 0.f);
            acc1 += fmaxf(t1 + __uint_as_float(u0 & 0xffff0000u), 0.f);
            acc0 += fmaxf(t0 + __uint_as_float(u1 << 16), 0.f);
            acc1 += fmaxf(t1 + __uint_as_float(u1 & 0xffff0000u), 0.f);
            acc0 += fmaxf(t0 + __uint_as_float(u2 << 16), 0.f);
            acc1 += fmaxf(t1 + __uint_as_float(u2 & 0xffff0000u), 0.f);
            acc0 += fmaxf(t0 + __uint_as_float(u3 << 16), 0.f);
            acc1 += fmaxf(t1 + __uint_as_float(u3 & 0xffff0000u), 0.f);
            acc0 += fmaxf(t0 + __uint_as_float(u4 << 16), 0.f);
            acc1 += fmaxf(t1 + __uint_as_float(u4 & 0xffff0000u), 0.f);
            acc0 += fmaxf(t0 + __uint_as_float(u5 << 16), 0.f);
            acc1 += fmaxf(t1 + __uint_as_float(u5 & 0xffff0000u), 0.f);
            acc0 += fmaxf(t0 + __uint_as_float(u6 << 16), 0.f);
            acc1 += fmaxf(t1 + __uint_as_float(u6 & 0xffff0000u), 0.f);
            acc0 += fmaxf(t0 + __uint_as_float(u7 << 16), 0.f);
            acc1 += fmaxf(t1 + __uint_as_float(u7 & 0xffff0000u), 0.f);
        }
        for (; i + 4 <= cnt; i += 4) {
            int s0 = __builtin_amdgcn_readlane(sv, i);
            int s1 = __builtin_amdgcn_readlane(sv, i + 1);
            int s2 = __builtin_amdgcn_readlane(sv, i + 2);
            int s3 = __builtin_amdgcn_readlane(sv, i + 3);
            unsigned u0 = *(const unsigned*)(Bb + (size_t)s0 * H + 2 * lane);
            unsigned u1 = *(const unsigned*)(Bb + (size_t)s1 * H + 2 * lane);
            unsigned u2 = *(const unsigned*)(Bb + (size_t)s2 * H + 2 * lane);
            unsigned u3 = *(const unsigned*)(Bb + (size_t)s3 * H + 2 * lane);
            acc0 += fmaxf(t0 + __uint_as_float(u0 << 16), 0.f);
            acc1 += fmaxf(t1 + __uint_as_float(u0 & 0xffff0000u), 0.f);
            acc0 += fmaxf(t0 + __uint_as_float(u1 << 16), 0.f);
            acc1 += fmaxf(t1 + __uint_as_float(u1 & 0xffff0000u), 0.f);
            acc0 += fmaxf(t0 + __uint_as_float(u2 << 16), 0.f);
            acc1 += fmaxf(t1 + __uint_as_float(u2 & 0xffff0000u), 0.f);
            acc0 += fmaxf(t0 + __uint_as_float(u3 << 16), 0.f);
            acc1 += fmaxf(t1 + __uint_as_float(u3 & 0xffff0000u), 0.f);
        }
        for (; i < cnt; i++) {
            int s = __builtin_amdgcn_readlane(sv, i);
            unsigned u = *(const unsigned*)(Bb + (size_t)s * H + 2 * lane);
            acc0 += fmaxf(t0 + __uint_as_float(u << 16), 0.f);
            acc1 += fmaxf(t1 + __uint_as_float(u & 0xffff0000u), 0.f);
        }
        e0 += cnt;
    }
    // swizzled bf16 store of cols (2l, 2l+1) for node v
    int vt = v >> 4, n = v & 15;
    int kt = lane >> 4;
    int lane2 = ((lane >> 2) & 3) * 16 + n;
    m2sw[(((vt * 4 + kt) * 64 + lane2) << 2) + (lane & 3)] =
        f2bbits(acc0) | (f2bbits(acc1) << 16);
}

// ---------- MFMA: h2 = tanh([m2|h1]@Wu + xu + b_upd); col-sums -> atomic ssum ----------
__global__ void __launch_bounds__(256) k_h2(
        const unsigned short* __restrict__ m2sw,
        const unsigned short* __restrict__ h1sw,
        const unsigned short* __restrict__ Wusw, const float* __restrict__ xu,
        const float* __restrict__ b_upd, float* __restrict__ ssum) {
    int tid = threadIdx.x;
    int lane = tid & 63, w = tid >> 6;
    int vt = blockIdx.x;
    int v0 = vt * 16;
    f32x4 acc[2];
    acc[0] = (f32x4){0.f, 0.f, 0.f, 0.f};
    acc[1] = (f32x4){0.f, 0.f, 0.f, 0.f};
    int nt0 = 2 * w;
    #pragma unroll
    for (int kt = 0; kt < 8; kt++) {
        bf16x8 af;
        if (kt < 4)
            af = *(const bf16x8*)(m2sw + (((vt * 4 + kt) * 64 + lane) << 3));
        else
            af = *(const bf16x8*)(h1sw + (((vt * 4 + (kt - 4)) * 64 + lane) << 3));
        #pragma unroll
        for (int t = 0; t < 2; t++) {
            bf16x8 bfg = *(const bf16x8*)(Wusw + (((kt * 8 + nt0 + t) * 64 + lane) << 3));
            acc[t] = __builtin_amdgcn_mfma_f32_16x16x32_bf16(af, bfg, acc[t], 0, 0, 0);
        }
    }
    int col = lane & 15, rg = lane >> 4;
    #pragma unroll
    for (int t = 0; t < 2; t++) {
        int n = (nt0 + t) * 16 + col;
        float bu = b_upd[n];
        float s = 0.f;
        #pragma unroll
        for (int i = 0; i < 4; i++) {
            int v = v0 + rg * 4 + i;
            s += tanhf(acc[t][i] + xu[v * H + n] + bu);
        }
        s += __shfl_xor(s, 16);
        s += __shfl_xor(s, 32);
        if (rg == 0) atomicAdd(&ssum[n], s);
    }
}

// ---------- out = relu(ssum @ W_ro + b_ro), k-parallel ----------
__global__ void __launch_bounds__(1024) k_out(
        const float* __restrict__ ssum,
        const float* __restrict__ W_ro, const float* __restrict__ b_ro,
        float* __restrict__ out) {
    __shared__ float ss[H];
    __shared__ float red[8][H]; // 4 KB
    int tid = threadIdx.x;
    int j = tid & 127, g = tid >> 7; // 8 k-groups of 16
    if (tid < H) ss[tid] = ssum[tid];
    __syncthreads();
    float s = 0.f;
    #pragma unroll
    for (int q = 0; q < 16; q++) {
        int k = g * 16 + q;
        s += ss[k] * W_ro[k * H + j];
    }
    red[g][j] = s;
    __syncthreads();
    if (tid < H) {
        float acc = b_ro[tid];
        #pragma unroll
        for (int q = 0; q < 8; q++)
            acc += red[q][tid];
        out[tid] = fmaxf(acc, 0.f);
    }
}

extern "C" void kernel_launch(void* const* d_in, const int* in_sizes, int n_in,
                              void* d_out, int out_size, void* d_ws, size_t ws_size,
                              hipStream_t stream) {
    const float* data   = (const float*)d_in[0];
    const int*   esrc   = (const int*)d_in[1];
    const int*   edst   = (const int*)d_in[2];
    const float* W_emb  = (const float*)d_in[3];
    const float* b_emb  = (const float*)d_in[4];
    const float* W_msg  = (const float*)d_in[5];
    const float* b_msg  = (const float*)d_in[6];
    const float* W_upd  = (const float*)d_in[7];
    const float* b_upd  = (const float*)d_in[8];
    const float* W_ro   = (const float*)d_in[9];
    const float* b_ro   = (const float*)d_in[10];
    float* out = (float*)d_out;

    // workspace layout (16B-aligned chunks)
    float* xu    = (float*)d_ws;                 // N*H f32
    float* A     = xu + N_NODES * H;             // N*H f32
    unsigned short* h1sw = (unsigned short*)(A + N_NODES * H); // N*H bf16 (swizzled)
    unsigned short* Bb   = h1sw + N_NODES * H;   // N*H bf16 (linear)
    unsigned short* m2sw = Bb + N_NODES * H;     // N*H bf16 (swizzled)
    unsigned short* dsw  = m2sw + N_NODES * H;   // N*DATA_DIM bf16 (swizzled)
    unsigned short* Wmsw = dsw + N_NODES * DATA_DIM; // 32768 bf16
    unsigned short* Wusw = Wmsw + 32768;         // 32768 bf16
    unsigned short* Wfsw = Wusw + 32768;         // 8192 bf16
    float* ssum  = (float*)(Wfsw + 8192);        // H
    float* r     = ssum + H;                     // H
    float* c     = r + H;                        // H
    float* bx    = c + H;                        // H
    float* Wf    = bx + H;                       // 64*H
    int* degi    = (int*)(Wf + DATA_DIM * H);    // N
    int* offs    = degi + N_NODES;               // N+1
    int* cursor  = offs + N_NODES + 1;           // N
    int* srcp    = cursor + N_NODES;             // E

    k_pre<<<PRE_BLOCKS, 256, 0, stream>>>(W_emb, W_upd, b_emb, b_msg, W_msg, data,
                                          Wf, Wfsw, r, c, bx, Wmsw, Wusw,
                                          (unsigned int*)dsw, degi);
    k_deg<<<(N_EDGES + 255) / 256, 256, 0, stream>>>(edst, degi);
    k_scan<<<1, 1024, 0, stream>>>(degi, offs, cursor, ssum);
    k_scatter<<<(N_EDGES + 255) / 256, 256, 0, stream>>>(edst, esrc, cursor, srcp);
    k_xu_h1<<<(NVT + 3) / 4, 256, 0, stream>>>(dsw, Wfsw, bx, offs, c, b_upd,
                                               xu, h1sw);
    k_ab<<<(NVT + 3) / 4, 256, 0, stream>>>(h1sw, Wmsw, b_msg, A, Bb);
    k_edge<<<N_NODES / 4, 256, 0, stream>>>(offs, srcp, A, Bb, r,
                                            (unsigned int*)m2sw);
    k_h2<<<NVT, 256, 0, stream>>>(m2sw, h1sw, Wusw, xu, b_upd, ssum);
    k_out<<<1, 1024, 0, stream>>>(ssum, W_ro, b_ro, out);
}

// Round 10
// 158.174 us; speedup vs baseline: 1.7129x; 1.0063x over previous
//
#include <hip/hip_runtime.h>
#include <hip/hip_bf16.h>

#define N_NODES 20000
#define N_EDGES 320000
#define DATA_DIM 64
#define H 128
#define NVT (N_NODES / 16)   // 1250 node tiles

// k_pre block ranges
#define DSW_END   (65536 + N_NODES * 32)          // 705536
#define DEG_END   (DSW_END + N_NODES)             // 725536
#define SWZ_BLOCKS ((DEG_END + 255) / 256)        // 2835
#define PRE_BLOCKS (SWZ_BLOCKS + DATA_DIM + 1)    // +65

typedef __attribute__((ext_vector_type(8))) short bf16x8;
typedef __attribute__((ext_vector_type(4))) float f32x4;

__device__ __forceinline__ unsigned f2bbits(float x) { // fp32 -> bf16 bits (RNE)
    unsigned u = __float_as_uint(x);
    return (u + 0x7FFFu + ((u >> 16) & 1u)) >> 16;
}
__device__ __forceinline__ float blo(unsigned u) { return __uint_as_float(u << 16); }
__device__ __forceinline__ float bhi(unsigned u) { return __uint_as_float(u & 0xffff0000u); }

// ---------- mega-precompute: weight/data swizzles + Wfsw + r/c/bx + degi zero ----------
// slot map (cancels between A and B operands in MFMA): k = kt*32+(lane>>4)*8+j, m/n = lane&15
__global__ void k_pre(const float* __restrict__ W_emb, const float* __restrict__ W_upd,
                      const float* __restrict__ b_emb, const float* __restrict__ b_msg,
                      const float* __restrict__ W_msg, const float* __restrict__ data,
                      unsigned short* __restrict__ Wfsw,
                      float* __restrict__ r, float* __restrict__ c, float* __restrict__ bx,
                      unsigned short* __restrict__ Wmsw, unsigned short* __restrict__ Wusw,
                      unsigned int* __restrict__ data_sw, int* __restrict__ deg) {
    int tid = threadIdx.x;
    __shared__ float sh[H];
    if (blockIdx.x >= SWZ_BLOCKS) {
        int d = blockIdx.x - SWZ_BLOCKS;
        int j = tid & 127;
        bool lo = tid < 128;
        if (d < DATA_DIM) {
            if (lo) sh[j] = W_emb[d * H + j];
            __syncthreads();
            if (lo) {
                float acc = 0.f;
                for (int k = 0; k < H; k++)
                    acc += sh[k] * W_upd[(256 + k) * H + j];
                int kt = d >> 5, lane2 = ((d >> 3) & 3) * 16 + (j & 15), jj = d & 7;
                Wfsw[(((kt * 8 + (j >> 4)) * 64 + lane2) << 3) + jj] =
                    (unsigned short)f2bbits(acc);
            }
        } else {
            if (lo) {
                float rj = fmaxf(b_msg[j], 0.f);
                r[j] = rj;
                sh[j] = rj;
            }
            __syncthreads();
            if (lo) {
                float cj = 0.f, bxj = 0.f;
                for (int k = 0; k < H; k++) {
                    cj  += sh[k] * W_upd[k * H + j];            // Wu_m rows 0..127
                    bxj += b_emb[k] * W_upd[(256 + k) * H + j]; // Wu_x rows 256..383
                }
                c[j] = cj;
                bx[j] = bxj;
            }
        }
        return;
    }
    int gid = blockIdx.x * 256 + tid;
    if (gid < 32768) {
        int k = gid >> 8, n = gid & 255;
        float src = (n < 128) ? W_msg[k * H + n] : W_msg[(128 + k) * H + (n - 128)];
        int kt = k >> 5, nt = n >> 4;
        int lane = ((k >> 3) & 3) * 16 + (n & 15), j = k & 7;
        Wmsw[(((kt * 16 + nt) * 64 + lane) << 3) + j] = (unsigned short)f2bbits(src);
    } else if (gid < 65536) {
        int id2 = gid - 32768;
        int k = id2 >> 7, n = id2 & 127;
        float src = W_upd[k * H + n];
        int kt = k >> 5, nt = n >> 4;
        int lane = ((k >> 3) & 3) * 16 + (n & 15), j = k & 7;
        Wusw[(((kt * 8 + nt) * 64 + lane) << 3) + j] = (unsigned short)f2bbits(src);
    } else if (gid < DSW_END) {
        int id = gid - 65536;            // [0, N_NODES*32)
        int v = id >> 5, k = (id & 31) * 2;
        float2 dv = *(const float2*)(data + v * DATA_DIM + k);
        int vt = v >> 4, rr = v & 15;
        int kt = k >> 5;
        int lane2 = ((k >> 3) & 3) * 16 + rr, j = k & 7;
        data_sw[(((vt * 2 + kt) * 64 + lane2) << 2) + (j >> 1)] =
            f2bbits(dv.x) | (f2bbits(dv.y) << 16);
    } else if (gid < DEG_END) {
        deg[gid - DSW_END] = 0;
    }
}

// ---------- degree histogram over edge_dst ----------
__global__ void k_deg(const int* __restrict__ dst, int* __restrict__ deg) {
    int e = blockIdx.x * blockDim.x + threadIdx.x;
    if (e < N_EDGES) atomicAdd(&deg[dst[e]], 1);
}

// ---------- exclusive scan -> offs, cursor (also zeroes ssum) ----------
__global__ void k_scan(const int* __restrict__ deg, int* __restrict__ offs,
                       int* __restrict__ cursor, float* __restrict__ ssum) {
    __shared__ int buf[1024];
    int t = threadIdx.x;
    if (t < H) ssum[t] = 0.f;
    const int chunk = (N_NODES + 1023) / 1024; // 20
    int base = t * chunk;
    int s = 0;
    for (int i = 0; i < chunk; i++) {
        int idx = base + i;
        if (idx < N_NODES) s += deg[idx];
    }
    int val = s;
    for (int off = 1; off < 1024; off <<= 1) {
        buf[t] = val;
        __syncthreads();
        if (t >= off) val += buf[t - off];
        __syncthreads();
    }
    int run = val - s;
    for (int i = 0; i < chunk; i++) {
        int idx = base + i;
        if (idx < N_NODES) {
            offs[idx] = run;
            cursor[idx] = run;
            run += deg[idx];
        }
    }
    if (t == 1023) offs[N_NODES] = val;
}

// ---------- bucket-scatter SRC ids by dst ----------
__global__ void k_scatter(const int* __restrict__ dst, const int* __restrict__ src,
                          int* __restrict__ cursor, int* __restrict__ srcp) {
    int e = blockIdx.x * blockDim.x + threadIdx.x;
    if (e < N_EDGES) {
        int p = atomicAdd(&cursor[dst[e]], 1);
        srcp[p] = src[e];
    }
}

// ---------- fused MFMA: h1 tile (wave-private LDS + h1sw) then [A'|Bb] half ----------
// wave = (vt, half h): phase1 computes h1 = tanh(deg*c + data@Wf + bx + bu) fragments,
// stages them in LDS (h1sw tile layout); h==0 also stores h1sw. phase2: 32 MFMA with
// Wm half (h=0 -> A'+b_msg fp32, h=1 -> Bb bf16).
__global__ void __launch_bounds__(256) k_xab(
        const unsigned short* __restrict__ data_sw,
        const unsigned short* __restrict__ Wfsw,
        const float* __restrict__ bx, const int* __restrict__ offs,
        const float* __restrict__ c, const float* __restrict__ b_upd,
        const unsigned short* __restrict__ Wmsw, const float* __restrict__ b_msg,
        unsigned short* __restrict__ h1sw,
        float* __restrict__ A, unsigned short* __restrict__ Bb) {
    __shared__ unsigned short stage[4][4 * 64 * 8]; // 4 waves x 4 KB
    int tid = threadIdx.x;
    int lane = tid & 63, w = tid >> 6;
    int gid = blockIdx.x * 4 + w;      // 0..2499
    int vt = gid >> 1, h = gid & 1;
    if (vt >= NVT) return;
    int col = lane & 15, rg = lane >> 4;
    int v0 = vt * 16;
    // ---- phase 1: h1 tile ----
    {
        f32x4 acc[8];
        #pragma unroll
        for (int i = 0; i < 8; i++) acc[i] = (f32x4){0.f, 0.f, 0.f, 0.f};
        #pragma unroll
        for (int kt = 0; kt < 2; kt++) {
            bf16x8 af = *(const bf16x8*)(data_sw + (((vt * 2 + kt) * 64 + lane) << 3));
            #pragma unroll
            for (int nt = 0; nt < 8; nt++) {
                bf16x8 bfg = *(const bf16x8*)(Wfsw + (((kt * 8 + nt) * 64 + lane) << 3));
                acc[nt] = __builtin_amdgcn_mfma_f32_16x16x32_bf16(af, bfg, acc[nt], 0, 0, 0);
            }
        }
        float dvv[4];
        #pragma unroll
        for (int i = 0; i < 4; i++) {
            int v = v0 + rg * 4 + i;
            dvv[i] = (float)(offs[v + 1] - offs[v]);
        }
        #pragma unroll
        for (int nt = 0; nt < 8; nt++) {
            int n = nt * 16 + col;
            float bxn = bx[n], cn = c[n], bun = b_upd[n];
            int kt2 = n >> 5, lane2b = ((n >> 3) & 3) * 16, j2 = n & 7;
            #pragma unroll
            for (int i = 0; i < 4; i++) {
                int rr = rg * 4 + i;
                float hh = tanhf(dvv[i] * cn + acc[nt][i] + bxn + bun);
                stage[w][((kt2 * 64 + lane2b + rr) << 3) + j2] =
                    (unsigned short)f2bbits(hh);
            }
        }
    }
    // wave-local LDS dependency only (each wave wrote its whole region)
    if (h == 0) {
        #pragma unroll
        for (int kt = 0; kt < 4; kt++) {
            uint4 q = *(const uint4*)&stage[w][(kt * 64 + lane) << 3];
            *(uint4*)(h1sw + ((((size_t)vt * 4 + kt) * 64 + lane) << 3)) = q;
        }
    }
    // ---- phase 2: half-GEMM ----
    f32x4 acc2[8];
    #pragma unroll
    for (int i = 0; i < 8; i++) acc2[i] = (f32x4){0.f, 0.f, 0.f, 0.f};
    #pragma unroll
    for (int kt = 0; kt < 4; kt++) {
        bf16x8 af = *(const bf16x8*)&stage[w][(kt * 64 + lane) << 3];
        #pragma unroll
        for (int nt = 0; nt < 8; nt++) {
            bf16x8 bfg = *(const bf16x8*)(Wmsw + (((kt * 16 + h * 8 + nt) * 64 + lane) << 3));
            acc2[nt] = __builtin_amdgcn_mfma_f32_16x16x32_bf16(af, bfg, acc2[nt], 0, 0, 0);
        }
    }
    int vr = v0 + rg * 4;
    if (h == 0) {
        #pragma unroll
        for (int nt = 0; nt < 8; nt++) {
            int n = nt * 16 + col;
            float bm = b_msg[n];
            #pragma unroll
            for (int i = 0; i < 4; i++)
                A[(vr + i) * H + n] = acc2[nt][i] + bm;
        }
    } else {
        #pragma unroll
        for (int nt = 0; nt < 8; nt++) {
            int n = nt * 16 + col;
            #pragma unroll
            for (int i = 0; i < 4; i++)
                Bb[(vr + i) * H + n] = (unsigned short)f2bbits(acc2[nt][i]);
        }
    }
}

// ---------- edge reduce: one node/wave, pair-row gather (2 edges per VMEM) ----------
// lanes 0-31: even edges, lanes 32-63: odd edges; lane covers cols 4c..4c+3.
__global__ void __launch_bounds__(256) k_edge(
        const int* __restrict__ offs, const int* __restrict__ srcp,
        const float* __restrict__ A, const unsigned short* __restrict__ Bb,
        const float* __restrict__ r, unsigned int* __restrict__ m2sw) {
    int tid = threadIdx.x;
    int lane = tid & 63, w = tid >> 6;
    int v = blockIdx.x * 4 + w;
    if (v >= N_NODES) return;
    int cc = lane & 31, half = lane >> 5;
    float4 tv = *(const float4*)(A + (size_t)v * H + 4 * cc);
    float4 rv = *(const float4*)(r + 4 * cc);
    int e0 = offs[v], e1 = offs[v + 1];
    float dv = (float)(e1 - e0);
    float a0 = 0.f, a1 = 0.f, a2 = 0.f, a3 = 0.f;
    while (e0 < e1) {
        int cnt = e1 - e0;
        if (cnt > 64) cnt = 64;
        int sv = (lane < cnt) ? srcp[e0 + lane] : 0;
        int i = 0;
        for (; i + 16 <= cnt; i += 16) {
            uint2 u[8];
            #pragma unroll
            for (int j = 0; j < 8; j++) {
                int se = __builtin_amdgcn_readlane(sv, i + 2 * j);
                int so = __builtin_amdgcn_readlane(sv, i + 2 * j + 1);
                int s = half ? so : se;
                u[j] = *(const uint2*)(Bb + (size_t)s * H + 4 * cc);
            }
            #pragma unroll
            for (int j = 0; j < 8; j++) {
                a0 += fmaxf(tv.x + blo(u[j].x), 0.f);
                a1 += fmaxf(tv.y + bhi(u[j].x), 0.f);
                a2 += fmaxf(tv.z + blo(u[j].y), 0.f);
                a3 += fmaxf(tv.w + bhi(u[j].y), 0.f);
            }
        }
        for (; i + 2 <= cnt; i += 2) {
            int se = __builtin_amdgcn_readlane(sv, i);
            int so = __builtin_amdgcn_readlane(sv, i + 1);
            int s = half ? so : se;
            uint2 u = *(const uint2*)(Bb + (size_t)s * H + 4 * cc);
            a0 += fmaxf(tv.x + blo(u.x), 0.f);
            a1 += fmaxf(tv.y + bhi(u.x), 0.f);
            a2 += fmaxf(tv.z + blo(u.y), 0.f);
            a3 += fmaxf(tv.w + bhi(u.y), 0.f);
        }
        if (i < cnt) { // single tail edge: only even-half accumulates
            int s = __builtin_amdgcn_readlane(sv, i);
            uint2 u = *(const uint2*)(Bb + (size_t)s * H + 4 * cc);
            if (half == 0) {
                a0 += fmaxf(tv.x + blo(u.x), 0.f);
                a1 += fmaxf(tv.y + bhi(u.x), 0.f);
                a2 += fmaxf(tv.z + blo(u.y), 0.f);
                a3 += fmaxf(tv.w + bhi(u.y), 0.f);
            }
        }
        e0 += cnt;
    }
    a0 += __shfl_xor(a0, 32);
    a1 += __shfl_xor(a1, 32);
    a2 += __shfl_xor(a2, 32);
    a3 += __shfl_xor(a3, 32);
    if (half == 0) {
        a0 += dv * rv.x; a1 += dv * rv.y; a2 += dv * rv.z; a3 += dv * rv.w;
        int vt = v >> 4, rr = v & 15;
        // fragment layout (same map as h1sw): short idx for col n=4c+i, node rr
        int sbase = (((vt * 4 + (cc >> 3)) * 64 + ((cc >> 1) & 3) * 16 + rr) << 3)
                    + (cc & 1) * 4;
        unsigned int* p = m2sw + (sbase >> 1);
        p[0] = f2bbits(a0) | (f2bbits(a1) << 16);
        p[1] = f2bbits(a2) | (f2bbits(a3) << 16);
    }
}

// ---------- MFMA: h2 = tanh([m2|h1|data]@[Wu;Wf] + bx + b_upd); col-sums -> ssum ----------
// K = 320: m2sw kt0..3, h1sw kt4..7, dsw kt8..9 (xu folded into the GEMM)
__global__ void __launch_bounds__(256) k_h2(
        const unsigned short* __restrict__ m2sw,
        const unsigned short* __restrict__ h1sw,
        const unsigned short* __restrict__ data_sw,
        const unsigned short* __restrict__ Wusw,
        const unsigned short* __restrict__ Wfsw,
        const float* __restrict__ bx, const float* __restrict__ b_upd,
        float* __restrict__ ssum) {
    int tid = threadIdx.x;
    int lane = tid & 63, w = tid >> 6;
    int vt = blockIdx.x;
    f32x4 acc[2];
    acc[0] = (f32x4){0.f, 0.f, 0.f, 0.f};
    acc[1] = (f32x4){0.f, 0.f, 0.f, 0.f};
    int nt0 = 2 * w;
    #pragma unroll
    for (int kt = 0; kt < 8; kt++) {
        bf16x8 af;
        if (kt < 4)
            af = *(const bf16x8*)(m2sw + (((vt * 4 + kt) * 64 + lane) << 3));
        else
            af = *(const bf16x8*)(h1sw + (((vt * 4 + (kt - 4)) * 64 + lane) << 3));
        #pragma unroll
        for (int t = 0; t < 2; t++) {
            bf16x8 bfg = *(const bf16x8*)(Wusw + (((kt * 8 + nt0 + t) * 64 + lane) << 3));
            acc[t] = __builtin_amdgcn_mfma_f32_16x16x32_bf16(af, bfg, acc[t], 0, 0, 0);
        }
    }
    #pragma unroll
    for (int kt = 0; kt < 2; kt++) {
        bf16x8 af = *(const bf16x8*)(data_sw + (((vt * 2 + kt) * 64 + lane) << 3));
        #pragma unroll
        for (int t = 0; t < 2; t++) {
            bf16x8 bfg = *(const bf16x8*)(Wfsw + (((kt * 8 + nt0 + t) * 64 + lane) << 3));
            acc[t] = __builtin_amdgcn_mfma_f32_16x16x32_bf16(af, bfg, acc[t], 0, 0, 0);
        }
    }
    int col = lane & 15, rg = lane >> 4;
    #pragma unroll
    for (int t = 0; t < 2; t++) {
        int n = (nt0 + t) * 16 + col;
        float bias = bx[n] + b_upd[n];
        float s = 0.f;
        #pragma unroll
        for (int i = 0; i < 4; i++)
            s += tanhf(acc[t][i] + bias);
        s += __shfl_xor(s, 16);
        s += __shfl_xor(s, 32);
        if (rg == 0) atomicAdd(&ssum[n], s);
    }
}

// ---------- out = relu(ssum @ W_ro + b_ro), k-parallel ----------
__global__ void __launch_bounds__(1024) k_out(
        const float* __restrict__ ssum,
        const float* __restrict__ W_ro, const float* __restrict__ b_ro,
        float* __restrict__ out) {
    __shared__ float ss[H];
    __shared__ float red[8][H]; // 4 KB
    int tid = threadIdx.x;
    int j = tid & 127, g = tid >> 7; // 8 k-groups of 16
    if (tid < H) ss[tid] = ssum[tid];
    __syncthreads();
    float s = 0.f;
    #pragma unroll
    for (int q = 0; q < 16; q++) {
        int k = g * 16 + q;
        s += ss[k] * W_ro[k * H + j];
    }
    red[g][j] = s;
    __syncthreads();
    if (tid < H) {
        float acc = b_ro[tid];
        #pragma unroll
        for (int q = 0; q < 8; q++)
            acc += red[q][tid];
        out[tid] = fmaxf(acc, 0.f);
    }
}

extern "C" void kernel_launch(void* const* d_in, const int* in_sizes, int n_in,
                              void* d_out, int out_size, void* d_ws, size_t ws_size,
                              hipStream_t stream) {
    const float* data   = (const float*)d_in[0];
    const int*   esrc   = (const int*)d_in[1];
    const int*   edst   = (const int*)d_in[2];
    const float* W_emb  = (const float*)d_in[3];
    const float* b_emb  = (const float*)d_in[4];
    const float* W_msg  = (const float*)d_in[5];
    const float* b_msg  = (const float*)d_in[6];
    const float* W_upd  = (const float*)d_in[7];
    const float* b_upd  = (const float*)d_in[8];
    const float* W_ro   = (const float*)d_in[9];
    const float* b_ro   = (const float*)d_in[10];
    float* out = (float*)d_out;

    // workspace layout (16B-aligned chunks)
    float* A     = (float*)d_ws;                 // N*H f32
    unsigned short* h1sw = (unsigned short*)(A + N_NODES * H); // N*H bf16 (swizzled)
    unsigned short* Bb   = h1sw + N_NODES * H;   // N*H bf16 (linear)
    unsigned short* m2sw = Bb + N_NODES * H;     // N*H bf16 (swizzled)
    unsigned short* dsw  = m2sw + N_NODES * H;   // N*DATA_DIM bf16 (swizzled)
    unsigned short* Wmsw = dsw + N_NODES * DATA_DIM; // 32768 bf16
    unsigned short* Wusw = Wmsw + 32768;         // 32768 bf16
    unsigned short* Wfsw = Wusw + 32768;         // 8192 bf16
    float* ssum  = (float*)(Wfsw + 8192);        // H
    float* r     = ssum + H;                     // H
    float* c     = r + H;                        // H
    float* bx    = c + H;                        // H
    int* degi    = (int*)(bx + H);               // N
    int* offs    = degi + N_NODES;               // N+1
    int* cursor  = offs + N_NODES + 1;           // N
    int* srcp    = cursor + N_NODES;             // E

    k_pre<<<PRE_BLOCKS, 256, 0, stream>>>(W_emb, W_upd, b_emb, b_msg, W_msg, data,
                                          Wfsw, r, c, bx, Wmsw, Wusw,
                                          (unsigned int*)dsw, degi);
    k_deg<<<(N_EDGES + 255) / 256, 256, 0, stream>>>(edst, degi);
    k_scan<<<1, 1024, 0, stream>>>(degi, offs, cursor, ssum);
    k_scatter<<<(N_EDGES + 255) / 256, 256, 0, stream>>>(edst, esrc, cursor, srcp);
    k_xab<<<(NVT * 2 + 3) / 4, 256, 0, stream>>>(dsw, Wfsw, bx, offs, c, b_upd,
                                                 Wmsw, b_msg, h1sw, A, Bb);
    k_edge<<<N_NODES / 4, 256, 0, stream>>>(offs, srcp, A, Bb, r,
                                            (unsigned int*)m2sw);
    k_h2<<<NVT, 256, 0, stream>>>(m2sw, h1sw, dsw, Wusw, Wfsw, bx, b_upd, ssum);
    k_out<<<1, 1024, 0, stream>>>(ssum, W_ro, b_ro, out);
}